// Round 14
// baseline (388.944 us; speedup 1.0000x reference)
//
#include <hip/hip_runtime.h>
#include <hip/hip_bf16.h>
#include <stdint.h>

#define NN 40000
#define EE 640000
#define HD 128
#define TDIM 128
#define TB 64
#define NTILES (EE / TB)   // 10000
#define GRID 1536          // persistent: 6 blocks/CU (25.6 KB LDS), 24 waves/CU

typedef short  s16x8 __attribute__((ext_vector_type(8)));
typedef float  f32x4 __attribute__((ext_vector_type(4)));
typedef unsigned short u16;
typedef unsigned int   u32;

__device__ __forceinline__ u32 cvtpk(float lo, float hi) {
  u32 r; asm("v_cvt_pk_bf16_f32 %0, %1, %2" : "=v"(r) : "v"(lo), "v"(hi)); return r;
}
__device__ __forceinline__ float b2f_lo(u32 w){ union{u32 u; float f;} x; x.u = w << 16; return x.f; }
__device__ __forceinline__ float b2f_hi(u32 w){ union{u32 u; float f;} x; x.u = w & 0xffff0000u; return x.f; }
__device__ __forceinline__ u16 f2b(float f) {
  union { float f; u32 u; } x; x.f = f;
  u32 r = x.u + 0x7fffu + ((x.u >> 16) & 1u);
  return (u16)(r >> 16);
}

#define WSCALE 16.0f   // weights stored x16 in fp8; descale 1/16 after MFMA

// ---- FiLM params: film[0:128]=shift, film[128:256]=1+scale ----
__global__ void prep_film_kernel(const float* __restrict__ te, const float* __restrict__ tW,
                                 const float* __restrict__ tb, float* __restrict__ film) {
  __shared__ float s[TDIM];
  int t = threadIdx.x;
  if (t < TDIM) { float v = te[t]; s[t] = v * __builtin_amdgcn_rcpf(1.f + __expf(-v)); }
  __syncthreads();
  float acc = tb[t];
  #pragma unroll 8
  for (int k = 0; k < TDIM; ++k) acc = fmaf(s[k], tW[k * 256 + t], acc);
  film[t] = (t >= 128) ? (1.f + acc) : acc;
}

// ---- wPt[256][128]: wPt[c][k] = iW[(c>>7)*128 + k][c&127] ----
__global__ void prep_wpt_kernel(const float* __restrict__ iW, u16* __restrict__ wPt) {
  int idx = blockIdx.x * 256 + threadIdx.x;
  if (idx < 256 * 128) {
    int c = idx >> 7, k = idx & 127;
    wPt[idx] = f2b(iW[((c >> 7) * 128 + k) * HD + (c & 127)]);
  }
}

// ---- GEMM1 weights fp8 e4m3 (x16), fragment-ordered:
//      byte idx = ks*4096 + lg*1024 + n*128 + l15*8 + j ; k = ks*32+lg*8+j ; row=n*16+l15
__global__ void prep_ad_kernel(const float* __restrict__ iW, u16* __restrict__ wadWt) {
  int pidx = blockIdx.x * 256 + threadIdx.x;   // fp8 pair index
  if (pidx < 4096) {
    int idx = pidx * 2;
    int j0 = idx & 7, l15 = (idx >> 3) & 15, n = (idx >> 7) & 7, lg = (idx >> 10) & 3, ks = idx >> 12;
    int row = n * 16 + l15;
    int k0 = ks * 32 + lg * 8 + j0;
    float v0 = WSCALE * iW[(256 + k0) * HD + row];
    float v1 = WSCALE * iW[(256 + k0 + 1) * HD + row];
    u32 p = __builtin_amdgcn_cvt_pk_fp8_f32(v0, v1, 0, false);
    wadWt[pidx] = (u16)p;
  }
}

// ---- GEMM2 weights fp8 e4m3 (x16, FiLM-scaled), k-permuted + fragment-ordered ----
__global__ void prep_c1w_kernel(const float* __restrict__ c1W, const float* __restrict__ film,
                                u16* __restrict__ c1Wt) {
  int pidx = blockIdx.x * 256 + threadIdx.x;   // fp8 pair index
  if (pidx < 8192) {
    int idx = pidx * 2;
    int j0 = idx & 7, l15 = (idx >> 3) & 15, n = (idx >> 7) & 7, lg = (idx >> 10) & 3, kq = idx >> 12;
    int row = n * 16 + l15;
    int ch0 = (kq * 2 + (j0 >> 2)) * 16 + lg * 4 + (j0 & 3);
    int ch1 = (kq * 2 + ((j0 + 1) >> 2)) * 16 + lg * 4 + ((j0 + 1) & 3);
    float v0 = WSCALE * film[128 + ch0] * c1W[ch0 * HD + row];
    float v1 = WSCALE * film[128 + ch1] * c1W[ch1 * HD + row];
    u32 p = __builtin_amdgcn_cvt_pk_fp8_f32(v0, v1, 0, false);
    c1Wt[pidx] = (u16)p;
  }
}

// ---- biasp[c] = c1b[c] + sum_k shift[k] * c1W[k][c] ----
__global__ void prep_bias_kernel(const float* __restrict__ c1b, const float* __restrict__ film,
                                 const float* __restrict__ c1W, float* __restrict__ biasp) {
  int t = threadIdx.x;  // 0..127
  float acc = c1b[t];
  #pragma unroll 8
  for (int k = 0; k < 128; ++k) acc = fmaf(film[k], c1W[k * HD + t], acc);
  biasp[t] = acc;
}

// ---- P[node][256] bf16 in fragment-permuted order ----
__global__ __launch_bounds__(256) void prep_P_kernel(const float* __restrict__ h,
                                                     const u16* __restrict__ wPt,
                                                     const float* __restrict__ ib,
                                                     u16* __restrict__ P) {
  __shared__ u16 sWp[256][136];
  __shared__ float sib[HD];
  int t = threadIdx.x;
  if (t < 128) sib[t] = ib[t];
  {
    const u16* src = wPt + t * 128;
    #pragma unroll
    for (int i = 0; i < 16; ++i)
      *(uint4*)&sWp[t][i * 8] = *(const uint4*)(src + i * 8);
  }
  int wave = t >> 6, lane = t & 63, l15 = lane & 15, lg = lane >> 4;
  int node = blockIdx.x * 64 + wave * 16 + l15;
  uint4 hb[4];
  const float* hr = h + (size_t)node * HD + lg * 8;
  #pragma unroll
  for (int c = 0; c < 4; ++c) {
    float4 a = *(const float4*)(hr + c * 32);
    float4 b = *(const float4*)(hr + c * 32 + 4);
    hb[c].x = cvtpk(a.x, a.y); hb[c].y = cvtpk(a.z, a.w);
    hb[c].z = cvtpk(b.x, b.y); hb[c].w = cvtpk(b.z, b.w);
  }
  __syncthreads();
  f32x4 acc[16];
  #pragma unroll
  for (int n = 0; n < 16; ++n) acc[n] = (f32x4){0.f, 0.f, 0.f, 0.f};
  #pragma unroll
  for (int c = 0; c < 4; ++c) {
    s16x8 bF = *(const s16x8*)&hb[c];
    #pragma unroll
    for (int n = 0; n < 16; ++n) {
      s16x8 aF = *(const s16x8*)&sWp[n * 16 + l15][c * 32 + lg * 8];
      acc[n] = __builtin_amdgcn_mfma_f32_16x16x32_bf16(aF, bF, acc[n], 0, 0, 0);
    }
  }
  u16* dst = P + (size_t)node * 256;
  #pragma unroll
  for (int n = 0; n < 16; ++n) {
    int cb = n * 16 + lg * 4;
    float a0 = acc[n][0], a1 = acc[n][1], a2 = acc[n][2], a3 = acc[n][3];
    if (n < 8) { a0 += sib[cb]; a1 += sib[cb + 1]; a2 += sib[cb + 2]; a3 += sib[cb + 3]; }
    int slot = (n < 8) ? (lg * 32 + n * 4) : (128 + lg * 32 + (n - 8) * 4);
    uint2 wv; wv.x = cvtpk(a0, a1); wv.y = cvtpk(a2, a3);
    *(uint2*)(dst + slot) = wv;
  }
}

// ---- out = pos ----
__global__ void copy_pos_kernel(const float* __restrict__ pos, float* __restrict__ out) {
  int i = blockIdx.x * 256 + threadIdx.x;
  if (i < NN * 3) out[i] = pos[i];
}

// ---- small prefetch state ----
struct PfS {
  int ri, ci;
  float4 a0, a1, d0, d1;
  float p0x, p0y, p0z, p1x, p1y, p1z;
};

// ---- persistent fused edge kernel: fp8 weights, 25.6 KB LDS, 256 thr, 6 blocks/CU ----
__global__ __launch_bounds__(256, 4) void edge_kernel(
    const float* __restrict__ pos,
    const float* __restrict__ edge_attr,
    const float* __restrict__ dist,
    const float* __restrict__ c2w,
    const float* __restrict__ cn_scale,
    const int*   __restrict__ eidx,
    const u16*   __restrict__ P,       // [N][256] bf16, fragment-permuted
    const u16*   __restrict__ wadWt,   // 8 KB fp8 fragment-ordered GEMM1 weights
    const u16*   __restrict__ c1Wt,    // 16 KB fp8 fragment-ordered, k-permuted GEMM2 weights
    const float* __restrict__ biasp,   // [128]
    float*       __restrict__ out)
{
  __shared__ u16   sW1[4096];    // 8 KB fp8
  __shared__ u16   sW2[8192];    // 16 KB fp8
  __shared__ float sC1b[HD];
  __shared__ float sC2w[HD];

  const int t    = threadIdx.x;
  const int lane = t & 63;
  const int wave = t >> 6;        // 0..3
  const int l15  = lane & 15;
  const int lg   = lane >> 4;
  const int wv   = wave * 16 + l15;   // edge offset in tile, 0..63

  if (t < HD) { sC1b[t] = biasp[t]; sC2w[t] = c2w[t]; }
  {
    const uint4* s1 = (const uint4*)wadWt;   // 512 uint4
    uint4* d1 = (uint4*)sW1;
    #pragma unroll
    for (int i = 0; i < 2; ++i) d1[t + i * 256] = s1[t + i * 256];
    const uint4* s2 = (const uint4*)c1Wt;    // 1024 uint4
    uint4* d2 = (uint4*)sW2;
    #pragma unroll
    for (int i = 0; i < 4; ++i) d2[t + i * 256] = s2[t + i * 256];
  }

  const float cns = cn_scale[0];
  const int bb8 = lg * 1024 + l15 * 8;   // byte base within each 4KB fp8 k-panel

  auto pf_idx_ad = [&](PfS& p, int tile) {
    int e = tile * TB + wv;
    p.ri = eidx[e];
    p.ci = eidx[EE + e];
    const float* pa = edge_attr + (size_t)e * 32 + lg * 8;
    const float* pd = dist      + (size_t)e * 32 + lg * 8;
    p.a0 = *(const float4*)(pa); p.a1 = *(const float4*)(pa + 4);
    p.d0 = *(const float4*)(pd); p.d1 = *(const float4*)(pd + 4);
  };
  auto pf_pos = [&](PfS& p) {
    p.p0x = pos[p.ri * 3 + 0]; p.p0y = pos[p.ri * 3 + 1]; p.p0z = pos[p.ri * 3 + 2];
    p.p1x = pos[p.ci * 3 + 0]; p.p1y = pos[p.ci * 3 + 1]; p.p1z = pos[p.ci * 3 + 2];
  };

  PfS A, B;
  pf_idx_ad(A, blockIdx.x);
  pf_pos(A);

  // prologue: P gathers for the first tile
  uint4 pra0, pra1, pra2, pra3, pca0, pca1, pca2, pca3;
  {
    const u16* pr = P + (size_t)A.ri * 256 + lg * 32;
    const u16* pc = P + (size_t)A.ci * 256 + 128 + lg * 32;
    pra0 = *(const uint4*)(pr);      pra1 = *(const uint4*)(pr + 8);
    pra2 = *(const uint4*)(pr + 16); pra3 = *(const uint4*)(pr + 24);
    pca0 = *(const uint4*)(pc);      pca1 = *(const uint4*)(pc + 8);
    pca2 = *(const uint4*)(pc + 16); pca3 = *(const uint4*)(pc + 24);
  }

  __syncthreads();   // only barrier: weights + consts visible

  for (int tile = blockIdx.x; tile < NTILES; tile += GRID) {
    int tn = tile + GRID; if (tn >= NTILES) tn = tile;

    // (1) next tile's independent loads — in flight across this tile
    pf_idx_ad(B, tn);

    // (2) pack features to fp8 (x1; weights carry x16)
    long ef0, ef1;
    {
      u32 a0 = __builtin_amdgcn_cvt_pk_fp8_f32(A.a0.x, A.a0.y, 0, false);
      a0 = __builtin_amdgcn_cvt_pk_fp8_f32(A.a0.z, A.a0.w, a0, true);
      u32 a1 = __builtin_amdgcn_cvt_pk_fp8_f32(A.a1.x, A.a1.y, 0, false);
      a1 = __builtin_amdgcn_cvt_pk_fp8_f32(A.a1.z, A.a1.w, a1, true);
      u32 d0 = __builtin_amdgcn_cvt_pk_fp8_f32(A.d0.x, A.d0.y, 0, false);
      d0 = __builtin_amdgcn_cvt_pk_fp8_f32(A.d0.z, A.d0.w, d0, true);
      u32 d1 = __builtin_amdgcn_cvt_pk_fp8_f32(A.d1.x, A.d1.y, 0, false);
      d1 = __builtin_amdgcn_cvt_pk_fp8_f32(A.d1.z, A.d1.w, d1, true);
      ef0 = (long)(((unsigned long long)a1 << 32) | a0);
      ef1 = (long)(((unsigned long long)d1 << 32) | d0);
    }

    // (3) GEMM1: Q = [attr|dist] @ iW_ad (fp8), immediate-offset ds_read_b64
    f32x4 acc[8];
    #pragma unroll
    for (int n = 0; n < 8; ++n) acc[n] = (f32x4){0.f, 0.f, 0.f, 0.f};
    #pragma unroll
    for (int ks = 0; ks < 2; ++ks) {
      long bF = (ks == 0) ? ef0 : ef1;
      #pragma unroll
      for (int n = 0; n < 8; ++n) {
        long aF = *(const long*)((const char*)sW1 + ks * 4096 + bb8 + n * 128);
        acc[n] = __builtin_amdgcn_mfma_f32_16x16x32_fp8_fp8(aF, bF, acc[n], 0, 0, 0);
      }
    }

    // (4) x = Q/16 + P_r + P_c; LN stats with 4-way partial chains
    float x[8][4];
    float s0=0.f,s1=0.f,s2=0.f,s3=0.f, q0=0.f,q1=0.f,q2=0.f,q3=0.f;
    #pragma unroll
    for (int i = 0; i < 4; ++i) {
      uint4 pa = (i == 0) ? pra0 : (i == 1) ? pra1 : (i == 2) ? pra2 : pra3;
      uint4 pc = (i == 0) ? pca0 : (i == 1) ? pca1 : (i == 2) ? pca2 : pca3;
      float v0 = fmaf(acc[2*i][0], 0.0625f, b2f_lo(pa.x) + b2f_lo(pc.x));
      float v1 = fmaf(acc[2*i][1], 0.0625f, b2f_hi(pa.x) + b2f_hi(pc.x));
      float v2 = fmaf(acc[2*i][2], 0.0625f, b2f_lo(pa.y) + b2f_lo(pc.y));
      float v3 = fmaf(acc[2*i][3], 0.0625f, b2f_hi(pa.y) + b2f_hi(pc.y));
      float v4 = fmaf(acc[2*i+1][0], 0.0625f, b2f_lo(pa.z) + b2f_lo(pc.z));
      float v5 = fmaf(acc[2*i+1][1], 0.0625f, b2f_hi(pa.z) + b2f_hi(pc.z));
      float v6 = fmaf(acc[2*i+1][2], 0.0625f, b2f_lo(pa.w) + b2f_lo(pc.w));
      float v7 = fmaf(acc[2*i+1][3], 0.0625f, b2f_hi(pa.w) + b2f_hi(pc.w));
      x[2*i][0]=v0; x[2*i][1]=v1; x[2*i][2]=v2; x[2*i][3]=v3;
      x[2*i+1][0]=v4; x[2*i+1][1]=v5; x[2*i+1][2]=v6; x[2*i+1][3]=v7;
      s0 += v0 + v4;  s1 += v1 + v5;  s2 += v2 + v6;  s3 += v3 + v7;
      q0 = fmaf(v0,v0,q0); q1 = fmaf(v1,v1,q1); q2 = fmaf(v2,v2,q2); q3 = fmaf(v3,v3,q3);
      q0 = fmaf(v4,v4,q0); q1 = fmaf(v5,v5,q1); q2 = fmaf(v6,v6,q2); q3 = fmaf(v7,v7,q3);
    }
    float sum = (s0 + s1) + (s2 + s3);
    float sq  = (q0 + q1) + (q2 + q3);
    sum += __shfl_xor(sum, 16); sum += __shfl_xor(sum, 32);
    sq  += __shfl_xor(sq,  16); sq  += __shfl_xor(sq,  32);
    float mean = sum * (1.f / 128.f);
    float var  = sq  * (1.f / 128.f) - mean * mean;
    float LA = rsqrtf(var + 1e-6f);
    float LB = -mean * LA;

    // (5) x-hat -> fp8, kept in registers (GEMM2 B-operand, k-permuted)
    u32 xp[8];
    #pragma unroll
    for (int n = 0; n < 8; ++n) {
      float y0 = fmaf(x[n][0], LA, LB);
      float y1 = fmaf(x[n][1], LA, LB);
      float y2 = fmaf(x[n][2], LA, LB);
      float y3 = fmaf(x[n][3], LA, LB);
      u32 w = __builtin_amdgcn_cvt_pk_fp8_f32(y0, y1, 0, false);
      w = __builtin_amdgcn_cvt_pk_fp8_f32(y2, y3, w, true);
      xp[n] = w;
    }

    // (6) GEMM2 (fp8): B from registers, A via immediate-offset ds_read_b64
    f32x4 acc2[8];
    #pragma unroll
    for (int n = 0; n < 8; ++n) acc2[n] = (f32x4){0.f, 0.f, 0.f, 0.f};
    #pragma unroll
    for (int kq = 0; kq < 4; ++kq) {
      long xF = (long)(((unsigned long long)xp[2*kq+1] << 32) | xp[2*kq]);
      #pragma unroll
      for (int n = 0; n < 8; ++n) {
        long aF = *(const long*)((const char*)sW2 + kq * 4096 + bb8 + n * 128);
        acc2[n] = __builtin_amdgcn_mfma_f32_16x16x32_fp8_fp8(aF, xF, acc2[n], 0, 0, 0);
      }
    }

    // (7) silu -> dot(c2W) with 4-way partial chains (descale 1/16)
    float z0=0.f, z1=0.f, z2=0.f, z3=0.f;
    #pragma unroll
    for (int n = 0; n < 8; ++n) {
      int cb = n * 16 + lg * 4;
      f32x4 cb4 = *(const f32x4*)&sC1b[cb];
      f32x4 cw4 = *(const f32x4*)&sC2w[cb];
      float y0 = fmaf(acc2[n][0], 0.0625f, cb4[0]);
      float y1 = fmaf(acc2[n][1], 0.0625f, cb4[1]);
      float y2 = fmaf(acc2[n][2], 0.0625f, cb4[2]);
      float y3 = fmaf(acc2[n][3], 0.0625f, cb4[3]);
      z0 = fmaf(y0 * __builtin_amdgcn_rcpf(1.f + __expf(-y0)), cw4[0], z0);
      z1 = fmaf(y1 * __builtin_amdgcn_rcpf(1.f + __expf(-y1)), cw4[1], z1);
      z2 = fmaf(y2 * __builtin_amdgcn_rcpf(1.f + __expf(-y2)), cw4[2], z2);
      z3 = fmaf(y3 * __builtin_amdgcn_rcpf(1.f + __expf(-y3)), cw4[3], z3);
    }
    float z = (z0 + z1) + (z2 + z3);
    z += __shfl_xor(z, 16); z += __shfl_xor(z, 32);

    // (8) depth-1 prefetch: next tile's pos + P rows
    pf_pos(B);
    uint4 qra0, qra1, qra2, qra3, qca0, qca1, qca2, qca3;
    {
      const u16* pr = P + (size_t)B.ri * 256 + lg * 32;
      const u16* pc = P + (size_t)B.ci * 256 + 128 + lg * 32;
      qra0 = *(const uint4*)(pr);      qra1 = *(const uint4*)(pr + 8);
      qra2 = *(const uint4*)(pr + 16); qra3 = *(const uint4*)(pr + 24);
      qca0 = *(const uint4*)(pc);      qca1 = *(const uint4*)(pc + 8);
      qca2 = *(const uint4*)(pc + 16); qca3 = *(const uint4*)(pc + 24);
    }

    // (9) tanh -> scatter
    if (lg < 3) {
      float zc = fminf(fmaxf(z, -15.f), 15.f);
      float ez = __expf(2.f * zc);
      float inv = (ez - 1.f) * __builtin_amdgcn_rcpf(ez + 1.f);
      float dx = A.p0x - A.p1x, dy = A.p0y - A.p1y, dz = A.p0z - A.p1z;
      float nrm = sqrtf(fmaf(dx, dx, fmaf(dy, dy, dz * dz)));
      float sc  = cns * inv * __builtin_amdgcn_rcpf(fmaxf(nrm, 1e-8f));
      float d   = (lg == 0) ? dx : ((lg == 1) ? dy : dz);
      atomicAdd(out + (size_t)A.ri * 3 + lg, d * sc);
    }

    A = B;
    pra0 = qra0; pra1 = qra1; pra2 = qra2; pra3 = qra3;
    pca0 = qca0; pca1 = qca1; pca2 = qca2; pca3 = qca3;
  }
}

extern "C" void kernel_launch(void* const* d_in, const int* in_sizes, int n_in,
                              void* d_out, int out_size, void* d_ws, size_t ws_size,
                              hipStream_t stream) {
  const float* h         = (const float*)d_in[0];
  const float* pos       = (const float*)d_in[1];
  const float* edge_attr = (const float*)d_in[2];
  const float* dist      = (const float*)d_in[3];
  const float* te        = (const float*)d_in[4];
  const float* tW        = (const float*)d_in[5];
  const float* tb        = (const float*)d_in[6];
  const float* iW        = (const float*)d_in[7];
  const float* ib        = (const float*)d_in[8];
  const float* c1W       = (const float*)d_in[9];
  const float* c1b       = (const float*)d_in[10];
  const float* c2W       = (const float*)d_in[11];
  const float* cn        = (const float*)d_in[12];
  const int*   eidx      = (const int*)d_in[13];
  float* out = (float*)d_out;

  char* ws = (char*)d_ws;
  u16*   P      = (u16*)(ws);                    // 40000*256*2 = 20,480,000 B
  u16*   wPt    = (u16*)(ws + 20480000);         // 65,536 B
  u16*   wadWt  = (u16*)(ws + 20545536);         // 8,192 B (fp8)
  u16*   c1Wt   = (u16*)(ws + 20553728);         // 16,384 B (fp8)
  float* film   = (float*)(ws + 20570112);       // 1,024 B
  float* biasp  = (float*)(ws + 20571136);       // 512 B

  hipLaunchKernelGGL(prep_film_kernel, dim3(1),   dim3(256), 0, stream, te, tW, tb, film);
  hipLaunchKernelGGL(prep_wpt_kernel,  dim3(128), dim3(256), 0, stream, iW, wPt);
  hipLaunchKernelGGL(prep_ad_kernel,   dim3(16),  dim3(256), 0, stream, iW, wadWt);
  hipLaunchKernelGGL(prep_c1w_kernel,  dim3(32),  dim3(256), 0, stream, c1W, film, c1Wt);
  hipLaunchKernelGGL(prep_bias_kernel, dim3(1),   dim3(128), 0, stream, c1b, film, c1W, biasp);
  hipLaunchKernelGGL(prep_P_kernel,    dim3(625), dim3(256), 0, stream, h, wPt, ib, P);
  hipLaunchKernelGGL(copy_pos_kernel,  dim3(469), dim3(256), 0, stream, pos, out);
  hipLaunchKernelGGL(edge_kernel,      dim3(GRID), dim3(256), 0, stream,
                     pos, edge_attr, dist, c2W, cn, eidx,
                     P, wadWt, c1Wt, biasp, out);
}

// Round 15
// 157.593 us; speedup vs baseline: 2.4680x; 2.4680x over previous
//
#include <hip/hip_runtime.h>
#include <hip/hip_bf16.h>
#include <stdint.h>

#define NN 40000
#define EE 640000
#define HD 128
#define TDIM 128
#define TB 128
#define NTILES (EE / TB)   // 5000
#define GRID 768           // persistent: target 3 blocks/CU (41.2 KB LDS)

typedef short  s16x8 __attribute__((ext_vector_type(8)));
typedef float  f32x4 __attribute__((ext_vector_type(4)));
typedef unsigned int u32x4 __attribute__((ext_vector_type(4)));
typedef unsigned short u16;
typedef unsigned int   u32;

__device__ __forceinline__ u32 cvtpk(float lo, float hi) {
  u32 r; asm("v_cvt_pk_bf16_f32 %0, %1, %2" : "=v"(r) : "v"(lo), "v"(hi)); return r;
}
__device__ __forceinline__ float b2f_lo(u32 w){ union{u32 u; float f;} x; x.u = w << 16; return x.f; }
__device__ __forceinline__ float b2f_hi(u32 w){ union{u32 u; float f;} x; x.u = w & 0xffff0000u; return x.f; }
__device__ __forceinline__ u16 f2b(float f) {
  union { float f; u32 u; } x; x.f = f;
  u32 r = x.u + 0x7fffu + ((x.u >> 16) & 1u);
  return (u16)(r >> 16);
}

#define WSCALE 16.0f   // GEMM1 fp8 weights stored x16; descale 1/16 after MFMA

// ---- FiLM params: film[0:128]=shift, film[128:256]=1+scale ----
__global__ void prep_film_kernel(const float* __restrict__ te, const float* __restrict__ tW,
                                 const float* __restrict__ tb, float* __restrict__ film) {
  __shared__ float s[TDIM];
  int t = threadIdx.x;
  if (t < TDIM) { float v = te[t]; s[t] = v * __builtin_amdgcn_rcpf(1.f + __expf(-v)); }
  __syncthreads();
  float acc = tb[t];
  #pragma unroll 8
  for (int k = 0; k < TDIM; ++k) acc = fmaf(s[k], tW[k * 256 + t], acc);
  film[t] = (t >= 128) ? (1.f + acc) : acc;
}

// ---- wPt[256][128]: wPt[c][k] = iW[(c>>7)*128 + k][c&127] ----
__global__ void prep_wpt_kernel(const float* __restrict__ iW, u16* __restrict__ wPt) {
  int idx = blockIdx.x * 256 + threadIdx.x;
  if (idx < 256 * 128) {
    int c = idx >> 7, k = idx & 127;
    wPt[idx] = f2b(iW[((c >> 7) * 128 + k) * HD + (c & 127)]);
  }
}

// ---- GEMM1 weights fp8 e4m3 (x16), fragment-ordered:
//      byte idx = ks*4096 + lg*1024 + n*128 + l15*8 + j ; k = ks*32+lg*8+j ; row=n*16+l15
__global__ void prep_ad_kernel(const float* __restrict__ iW, u16* __restrict__ wadWt) {
  int pidx = blockIdx.x * 256 + threadIdx.x;   // fp8 pair index
  if (pidx < 4096) {
    int idx = pidx * 2;
    int j0 = idx & 7, l15 = (idx >> 3) & 15, n = (idx >> 7) & 7, lg = (idx >> 10) & 3, ks = idx >> 12;
    int row = n * 16 + l15;
    int k0 = ks * 32 + lg * 8 + j0;
    float v0 = WSCALE * iW[(256 + k0) * HD + row];
    float v1 = WSCALE * iW[(256 + k0 + 1) * HD + row];
    u32 p = __builtin_amdgcn_cvt_pk_fp8_f32(v0, v1, 0, false);
    wadWt[pidx] = (u16)p;
  }
}

// ---- GEMM2 weights bf16, k-permuted (register-local B) AND fragment-ordered ----
__global__ void prep_c1w_kernel(const float* __restrict__ c1W, const float* __restrict__ film,
                                u16* __restrict__ c1Wt) {
  int idx = blockIdx.x * 256 + threadIdx.x;
  if (idx < 16384) {
    int j = idx & 7, l15 = (idx >> 3) & 15, n = (idx >> 7) & 7, lg = (idx >> 10) & 3, kq = idx >> 12;
    int row = n * 16 + l15;
    int ch = (kq * 2 + (j >> 2)) * 16 + lg * 4 + (j & 3);
    c1Wt[idx] = f2b(film[128 + ch] * c1W[ch * HD + row]);
  }
}

// ---- biasp[c] = c1b[c] + sum_k shift[k] * c1W[k][c] ----
__global__ void prep_bias_kernel(const float* __restrict__ c1b, const float* __restrict__ film,
                                 const float* __restrict__ c1W, float* __restrict__ biasp) {
  int t = threadIdx.x;  // 0..127
  float acc = c1b[t];
  #pragma unroll 8
  for (int k = 0; k < 128; ++k) acc = fmaf(film[k], c1W[k * HD + t], acc);
  biasp[t] = acc;
}

// ---- P[node][256] bf16 in fragment-permuted order ----
__global__ __launch_bounds__(256) void prep_P_kernel(const float* __restrict__ h,
                                                     const u16* __restrict__ wPt,
                                                     const float* __restrict__ ib,
                                                     u16* __restrict__ P) {
  __shared__ u16 sWp[256][136];
  __shared__ float sib[HD];
  int t = threadIdx.x;
  if (t < 128) sib[t] = ib[t];
  {
    const u16* src = wPt + t * 128;
    #pragma unroll
    for (int i = 0; i < 16; ++i)
      *(uint4*)&sWp[t][i * 8] = *(const uint4*)(src + i * 8);
  }
  int wave = t >> 6, lane = t & 63, l15 = lane & 15, lg = lane >> 4;
  int node = blockIdx.x * 64 + wave * 16 + l15;
  uint4 hb[4];
  const float* hr = h + (size_t)node * HD + lg * 8;
  #pragma unroll
  for (int c = 0; c < 4; ++c) {
    float4 a = *(const float4*)(hr + c * 32);
    float4 b = *(const float4*)(hr + c * 32 + 4);
    hb[c].x = cvtpk(a.x, a.y); hb[c].y = cvtpk(a.z, a.w);
    hb[c].z = cvtpk(b.x, b.y); hb[c].w = cvtpk(b.z, b.w);
  }
  __syncthreads();
  f32x4 acc[16];
  #pragma unroll
  for (int n = 0; n < 16; ++n) acc[n] = (f32x4){0.f, 0.f, 0.f, 0.f};
  #pragma unroll
  for (int c = 0; c < 4; ++c) {
    s16x8 bF = *(const s16x8*)&hb[c];
    #pragma unroll
    for (int n = 0; n < 16; ++n) {
      s16x8 aF = *(const s16x8*)&sWp[n * 16 + l15][c * 32 + lg * 8];
      acc[n] = __builtin_amdgcn_mfma_f32_16x16x32_bf16(aF, bF, acc[n], 0, 0, 0);
    }
  }
  u16* dst = P + (size_t)node * 256;
  #pragma unroll
  for (int n = 0; n < 16; ++n) {
    int cb = n * 16 + lg * 4;
    float a0 = acc[n][0], a1 = acc[n][1], a2 = acc[n][2], a3 = acc[n][3];
    if (n < 8) { a0 += sib[cb]; a1 += sib[cb + 1]; a2 += sib[cb + 2]; a3 += sib[cb + 3]; }
    int slot = (n < 8) ? (lg * 32 + n * 4) : (128 + lg * 32 + (n - 8) * 4);
    uint2 wv; wv.x = cvtpk(a0, a1); wv.y = cvtpk(a2, a3);
    *(uint2*)(dst + slot) = wv;
  }
}

// ---- out = pos ----
__global__ void copy_pos_kernel(const float* __restrict__ pos, float* __restrict__ out) {
  int i = blockIdx.x * 256 + threadIdx.x;
  if (i < NN * 3) out[i] = pos[i];
}

// ---- small prefetch state ----
struct PfS {
  int ri, ci;
  float4 a0, a1, d0, d1;
  float p0x, p0y, p0z, p1x, p1y, p1z;
};

// ---- persistent fused edge kernel: fp8 GEMM1 / bf16 GEMM2, 41.2 KB LDS ----
__global__ __launch_bounds__(512, 4) void edge_kernel(
    const float* __restrict__ pos,
    const float* __restrict__ edge_attr,
    const float* __restrict__ dist,
    const float* __restrict__ c2w,
    const float* __restrict__ cn_scale,
    const int*   __restrict__ eidx,
    const u16*   __restrict__ P,       // [N][256] bf16, fragment-permuted
    const u16*   __restrict__ wadWt,   // 8 KB fp8 fragment-ordered GEMM1 weights
    const u16*   __restrict__ c1Wt,    // 32 KB bf16 fragment-ordered, k-permuted GEMM2 weights
    const float* __restrict__ biasp,   // [128]
    float*       __restrict__ out)
{
  __shared__ u16   sW1[4096];    // 8 KB fp8
  __shared__ u16   sW2[16384];   // 32 KB bf16
  __shared__ float sC1b[HD];
  __shared__ float sC2w[HD];

  const int t    = threadIdx.x;
  const int lane = t & 63;
  const int wave = t >> 6;        // 0..7
  const int l15  = lane & 15;
  const int lg   = lane >> 4;
  const int wv   = wave * 16 + l15;   // edge offset in tile, 0..127

  if (t < HD) { sC1b[t] = biasp[t]; sC2w[t] = c2w[t]; }
  {
    const uint4* s1 = (const uint4*)wadWt;   // 512 uint4
    uint4* d1 = (uint4*)sW1;
    if (t < 512) d1[t] = s1[t];
    const uint4* s2 = (const uint4*)c1Wt;    // 2048 uint4
    uint4* d2 = (uint4*)sW2;
    #pragma unroll
    for (int i = 0; i < 4; ++i) d2[t + i * 512] = s2[t + i * 512];
  }

  const float cns = cn_scale[0];
  const int bb8   = lg * 1024 + l15 * 8;    // GEMM1 fp8: byte base in each 4KB k-panel
  const int bbase = lg * 2048 + l15 * 16;   // GEMM2 bf16: byte base in each 8KB k-panel

  auto pf_idx_ad = [&](PfS& p, int tile) {
    int e = tile * TB + wv;
    p.ri = eidx[e];
    p.ci = eidx[EE + e];
    const float* pa = edge_attr + (size_t)e * 32 + lg * 8;
    const float* pd = dist      + (size_t)e * 32 + lg * 8;
    p.a0 = *(const float4*)(pa); p.a1 = *(const float4*)(pa + 4);
    p.d0 = *(const float4*)(pd); p.d1 = *(const float4*)(pd + 4);
  };
  auto pf_pos = [&](PfS& p) {
    p.p0x = pos[p.ri * 3 + 0]; p.p0y = pos[p.ri * 3 + 1]; p.p0z = pos[p.ri * 3 + 2];
    p.p1x = pos[p.ci * 3 + 0]; p.p1y = pos[p.ci * 3 + 1]; p.p1z = pos[p.ci * 3 + 2];
  };

  PfS A, B;
  pf_idx_ad(A, blockIdx.x);
  pf_pos(A);

  // prologue: P gathers for the first tile
  uint4 pra0, pra1, pra2, pra3, pca0, pca1, pca2, pca3;
  {
    const u16* pr = P + (size_t)A.ri * 256 + lg * 32;
    const u16* pc = P + (size_t)A.ci * 256 + 128 + lg * 32;
    pra0 = *(const uint4*)(pr);      pra1 = *(const uint4*)(pr + 8);
    pra2 = *(const uint4*)(pr + 16); pra3 = *(const uint4*)(pr + 24);
    pca0 = *(const uint4*)(pc);      pca1 = *(const uint4*)(pc + 8);
    pca2 = *(const uint4*)(pc + 16); pca3 = *(const uint4*)(pc + 24);
  }

  __syncthreads();   // only barrier: weights + consts visible

  for (int tile = blockIdx.x; tile < NTILES; tile += GRID) {
    int tn = tile + GRID; if (tn >= NTILES) tn = tile;

    // (1) next tile's independent loads — in flight across this tile
    pf_idx_ad(B, tn);

    // (2) pack features to fp8 (x1; weights carry x16)
    long ef0, ef1;
    {
      u32 a0 = __builtin_amdgcn_cvt_pk_fp8_f32(A.a0.x, A.a0.y, 0, false);
      a0 = __builtin_amdgcn_cvt_pk_fp8_f32(A.a0.z, A.a0.w, a0, true);
      u32 a1 = __builtin_amdgcn_cvt_pk_fp8_f32(A.a1.x, A.a1.y, 0, false);
      a1 = __builtin_amdgcn_cvt_pk_fp8_f32(A.a1.z, A.a1.w, a1, true);
      u32 d0 = __builtin_amdgcn_cvt_pk_fp8_f32(A.d0.x, A.d0.y, 0, false);
      d0 = __builtin_amdgcn_cvt_pk_fp8_f32(A.d0.z, A.d0.w, d0, true);
      u32 d1 = __builtin_amdgcn_cvt_pk_fp8_f32(A.d1.x, A.d1.y, 0, false);
      d1 = __builtin_amdgcn_cvt_pk_fp8_f32(A.d1.z, A.d1.w, d1, true);
      ef0 = (long)(((unsigned long long)a1 << 32) | a0);
      ef1 = (long)(((unsigned long long)d1 << 32) | d0);
    }

    // (3) GEMM1 (fp8): Q = [attr|dist] @ iW_ad, immediate-offset ds_read_b64
    f32x4 acc[8];
    #pragma unroll
    for (int n = 0; n < 8; ++n) acc[n] = (f32x4){0.f, 0.f, 0.f, 0.f};
    #pragma unroll
    for (int ks = 0; ks < 2; ++ks) {
      long bF = (ks == 0) ? ef0 : ef1;
      #pragma unroll
      for (int n = 0; n < 8; ++n) {
        long aF = *(const long*)((const char*)sW1 + ks * 4096 + bb8 + n * 128);
        acc[n] = __builtin_amdgcn_mfma_f32_16x16x32_fp8_fp8(aF, bF, acc[n], 0, 0, 0);
      }
    }

    // (4) x = Q/16 + P_r + P_c; LN stats with 4-way partial chains
    float x[8][4];
    float s0=0.f,s1=0.f,s2=0.f,s3=0.f, q0=0.f,q1=0.f,q2=0.f,q3=0.f;
    #pragma unroll
    for (int i = 0; i < 4; ++i) {
      uint4 pa = (i == 0) ? pra0 : (i == 1) ? pra1 : (i == 2) ? pra2 : pra3;
      uint4 pc = (i == 0) ? pca0 : (i == 1) ? pca1 : (i == 2) ? pca2 : pca3;
      float v0 = fmaf(acc[2*i][0], 0.0625f, b2f_lo(pa.x) + b2f_lo(pc.x));
      float v1 = fmaf(acc[2*i][1], 0.0625f, b2f_hi(pa.x) + b2f_hi(pc.x));
      float v2 = fmaf(acc[2*i][2], 0.0625f, b2f_lo(pa.y) + b2f_lo(pc.y));
      float v3 = fmaf(acc[2*i][3], 0.0625f, b2f_hi(pa.y) + b2f_hi(pc.y));
      float v4 = fmaf(acc[2*i+1][0], 0.0625f, b2f_lo(pa.z) + b2f_lo(pc.z));
      float v5 = fmaf(acc[2*i+1][1], 0.0625f, b2f_hi(pa.z) + b2f_hi(pc.z));
      float v6 = fmaf(acc[2*i+1][2], 0.0625f, b2f_lo(pa.w) + b2f_lo(pc.w));
      float v7 = fmaf(acc[2*i+1][3], 0.0625f, b2f_hi(pa.w) + b2f_hi(pc.w));
      x[2*i][0]=v0; x[2*i][1]=v1; x[2*i][2]=v2; x[2*i][3]=v3;
      x[2*i+1][0]=v4; x[2*i+1][1]=v5; x[2*i+1][2]=v6; x[2*i+1][3]=v7;
      s0 += v0 + v4;  s1 += v1 + v5;  s2 += v2 + v6;  s3 += v3 + v7;
      q0 = fmaf(v0,v0,q0); q1 = fmaf(v1,v1,q1); q2 = fmaf(v2,v2,q2); q3 = fmaf(v3,v3,q3);
      q0 = fmaf(v4,v4,q0); q1 = fmaf(v5,v5,q1); q2 = fmaf(v6,v6,q2); q3 = fmaf(v7,v7,q3);
    }
    float sum = (s0 + s1) + (s2 + s3);
    float sq  = (q0 + q1) + (q2 + q3);
    sum += __shfl_xor(sum, 16); sum += __shfl_xor(sum, 32);
    sq  += __shfl_xor(sq,  16); sq  += __shfl_xor(sq,  32);
    float mean = sum * (1.f / 128.f);
    float var  = sq  * (1.f / 128.f) - mean * mean;
    float LA = rsqrtf(var + 1e-6f);
    float LB = -mean * LA;

    // (5) x-hat -> bf16 pairs in registers (GEMM2 B-operand, k-permuted)
    union { uint2 u2[8]; u32 w[16]; } xb;
    #pragma unroll
    for (int n = 0; n < 8; ++n) {
      float y0 = fmaf(x[n][0], LA, LB);
      float y1 = fmaf(x[n][1], LA, LB);
      float y2 = fmaf(x[n][2], LA, LB);
      float y3 = fmaf(x[n][3], LA, LB);
      xb.u2[n].x = cvtpk(y0, y1);
      xb.u2[n].y = cvtpk(y2, y3);
    }

    // (6) GEMM2 (bf16): B from registers, A via immediate-offset LDS
    f32x4 acc2[8];
    #pragma unroll
    for (int n = 0; n < 8; ++n) acc2[n] = (f32x4){0.f, 0.f, 0.f, 0.f};
    #pragma unroll
    for (int kq = 0; kq < 4; ++kq) {
      u32x4 xw = { xb.w[4*kq], xb.w[4*kq+1], xb.w[4*kq+2], xb.w[4*kq+3] };
      s16x8 xF = __builtin_bit_cast(s16x8, xw);
      #pragma unroll
      for (int n = 0; n < 8; ++n) {
        s16x8 aF = *(const s16x8*)((const char*)sW2 + kq * 8192 + bbase + n * 256);
        acc2[n] = __builtin_amdgcn_mfma_f32_16x16x32_bf16(aF, xF, acc2[n], 0, 0, 0);
      }
    }

    // (7) silu -> dot(c2W) with 4-way partial chains
    float z0=0.f, z1=0.f, z2=0.f, z3=0.f;
    #pragma unroll
    for (int n = 0; n < 8; ++n) {
      int cb = n * 16 + lg * 4;
      f32x4 cb4 = *(const f32x4*)&sC1b[cb];
      f32x4 cw4 = *(const f32x4*)&sC2w[cb];
      float y0 = acc2[n][0] + cb4[0];
      float y1 = acc2[n][1] + cb4[1];
      float y2 = acc2[n][2] + cb4[2];
      float y3 = acc2[n][3] + cb4[3];
      z0 = fmaf(y0 * __builtin_amdgcn_rcpf(1.f + __expf(-y0)), cw4[0], z0);
      z1 = fmaf(y1 * __builtin_amdgcn_rcpf(1.f + __expf(-y1)), cw4[1], z1);
      z2 = fmaf(y2 * __builtin_amdgcn_rcpf(1.f + __expf(-y2)), cw4[2], z2);
      z3 = fmaf(y3 * __builtin_amdgcn_rcpf(1.f + __expf(-y3)), cw4[3], z3);
    }
    float z = (z0 + z1) + (z2 + z3);
    z += __shfl_xor(z, 16); z += __shfl_xor(z, 32);

    // (8) depth-1 prefetch: next tile's pos + P rows
    pf_pos(B);
    uint4 qra0, qra1, qra2, qra3, qca0, qca1, qca2, qca3;
    {
      const u16* pr = P + (size_t)B.ri * 256 + lg * 32;
      const u16* pc = P + (size_t)B.ci * 256 + 128 + lg * 32;
      qra0 = *(const uint4*)(pr);      qra1 = *(const uint4*)(pr + 8);
      qra2 = *(const uint4*)(pr + 16); qra3 = *(const uint4*)(pr + 24);
      qca0 = *(const uint4*)(pc);      qca1 = *(const uint4*)(pc + 8);
      qca2 = *(const uint4*)(pc + 16); qca3 = *(const uint4*)(pc + 24);
    }

    // (9) tanh -> scatter
    if (lg < 3) {
      float zc = fminf(fmaxf(z, -15.f), 15.f);
      float ez = __expf(2.f * zc);
      float inv = (ez - 1.f) * __builtin_amdgcn_rcpf(ez + 1.f);
      float dx = A.p0x - A.p1x, dy = A.p0y - A.p1y, dz = A.p0z - A.p1z;
      float nrm = sqrtf(fmaf(dx, dx, fmaf(dy, dy, dz * dz)));
      float sc  = cns * inv * __builtin_amdgcn_rcpf(fmaxf(nrm, 1e-8f));
      float d   = (lg == 0) ? dx : ((lg == 1) ? dy : dz);
      atomicAdd(out + (size_t)A.ri * 3 + lg, d * sc);
    }

    A = B;
    pra0 = qra0; pra1 = qra1; pra2 = qra2; pra3 = qra3;
    pca0 = qca0; pca1 = qca1; pca2 = qca2; pca3 = qca3;
  }
}

extern "C" void kernel_launch(void* const* d_in, const int* in_sizes, int n_in,
                              void* d_out, int out_size, void* d_ws, size_t ws_size,
                              hipStream_t stream) {
  const float* h         = (const float*)d_in[0];
  const float* pos       = (const float*)d_in[1];
  const float* edge_attr = (const float*)d_in[2];
  const float* dist      = (const float*)d_in[3];
  const float* te        = (const float*)d_in[4];
  const float* tW        = (const float*)d_in[5];
  const float* tb        = (const float*)d_in[6];
  const float* iW        = (const float*)d_in[7];
  const float* ib        = (const float*)d_in[8];
  const float* c1W       = (const float*)d_in[9];
  const float* c1b       = (const float*)d_in[10];
  const float* c2W       = (const float*)d_in[11];
  const float* cn        = (const float*)d_in[12];
  const int*   eidx      = (const int*)d_in[13];
  float* out = (float*)d_out;

  char* ws = (char*)d_ws;
  u16*   P      = (u16*)(ws);                    // 40000*256*2 = 20,480,000 B
  u16*   wPt    = (u16*)(ws + 20480000);         // 65,536 B
  u16*   wadWt  = (u16*)(ws + 20545536);         // 8,192 B (fp8)
  u16*   c1Wt   = (u16*)(ws + 20553728);         // 32,768 B (bf16)
  float* film   = (float*)(ws + 20586496);       // 1,024 B
  float* biasp  = (float*)(ws + 20587520);       // 512 B

  hipLaunchKernelGGL(prep_film_kernel, dim3(1),   dim3(256), 0, stream, te, tW, tb, film);
  hipLaunchKernelGGL(prep_wpt_kernel,  dim3(128), dim3(256), 0, stream, iW, wPt);
  hipLaunchKernelGGL(prep_ad_kernel,   dim3(16),  dim3(256), 0, stream, iW, wadWt);
  hipLaunchKernelGGL(prep_c1w_kernel,  dim3(64),  dim3(256), 0, stream, c1W, film, c1Wt);
  hipLaunchKernelGGL(prep_bias_kernel, dim3(1),   dim3(128), 0, stream, c1b, film, c1W, biasp);
  hipLaunchKernelGGL(prep_P_kernel,    dim3(625), dim3(256), 0, stream, h, wPt, ib, P);
  hipLaunchKernelGGL(copy_pos_kernel,  dim3(469), dim3(256), 0, stream, pos, out);
  hipLaunchKernelGGL(edge_kernel,      dim3(GRID), dim3(512), 0, stream,
                     pos, edge_attr, dist, c2W, cn, eidx,
                     P, wadWt, c1Wt, biasp, out);
}

// Round 16
// 145.116 us; speedup vs baseline: 2.6802x; 1.0860x over previous
//
#include <hip/hip_runtime.h>
#include <hip/hip_bf16.h>
#include <hip/hip_fp16.h>
#include <stdint.h>

#define NN 40000
#define EE 640000
#define HD 128
#define TDIM 128
#define TB 256             // 8 waves x 32 edges
#define NTILES (EE / TB)   // 2500
#define GRID 512           // persistent: 2 blocks/CU

typedef short  s16x8  __attribute__((ext_vector_type(8)));
typedef float  f32x4  __attribute__((ext_vector_type(4)));
typedef float  f32x16 __attribute__((ext_vector_type(16)));
typedef unsigned int u32x4 __attribute__((ext_vector_type(4)));
typedef unsigned short u16;
typedef unsigned int   u32;

__device__ __forceinline__ u32 cvtpk(float lo, float hi) {
  u32 r; asm("v_cvt_pk_bf16_f32 %0, %1, %2" : "=v"(r) : "v"(lo), "v"(hi)); return r;
}
__device__ __forceinline__ u16 f2b(float f) {
  union { float f; u32 u; } x; x.f = f;
  u32 r = x.u + 0x7fffu + ((x.u >> 16) & 1u);
  return (u16)(r >> 16);
}

// ---- FiLM params: film[0:128]=shift, film[128:256]=1+scale ----
__global__ void prep_film_kernel(const float* __restrict__ te, const float* __restrict__ tW,
                                 const float* __restrict__ tb, float* __restrict__ film) {
  __shared__ float s[TDIM];
  int t = threadIdx.x;
  if (t < TDIM) { float v = te[t]; s[t] = v * __builtin_amdgcn_rcpf(1.f + __expf(-v)); }
  __syncthreads();
  float acc = tb[t];
  #pragma unroll 8
  for (int k = 0; k < TDIM; ++k) acc = fmaf(s[k], tW[k * 256 + t], acc);
  film[t] = (t >= 128) ? (1.f + acc) : acc;
}

// ---- wPt[256][128]: wPt[c][k] = iW[(c>>7)*128 + k][c&127] ----
__global__ void prep_wpt_kernel(const float* __restrict__ iW, u16* __restrict__ wPt) {
  int idx = blockIdx.x * 256 + threadIdx.x;
  if (idx < 256 * 128) {
    int c = idx >> 7, k = idx & 127;
    wPt[idx] = f2b(iW[((c >> 7) * 128 + k) * HD + (c & 127)]);
  }
}

// ---- GEMM1 weights bf16, 32x32 fragment-ordered:
//      idx = frag*512 + l*8 + j ; frag = ks*4+nb ; row = nb*32+(l&31) ; k = ks*16+(l>>5)*8+j
__global__ void prep_ad_kernel(const float* __restrict__ iW, u16* __restrict__ wadWt) {
  int idx = blockIdx.x * 256 + threadIdx.x;
  if (idx < 8192) {
    int j = idx & 7, l = (idx >> 3) & 63, frag = idx >> 9;
    int ks = frag >> 2, nb = frag & 3;
    int row = nb * 32 + (l & 31);
    int k = ks * 16 + (l >> 5) * 8 + j;
    wadWt[idx] = f2b(iW[(256 + k) * HD + row]);
  }
}

// ---- GEMM2 weights bf16, k-permuted + 32x32 fragment-ordered:
//      idx = frag*512 + l*8 + j ; frag = ks*4+nb (ks 0..7) ; c2 = nb*32+(l&31) ; h=l>>5
//      x-channel ch = 8*(2*ks + (j>>2)) + h*4 + (j&3) ; val = (1+scale[ch])*c1W[ch][c2]
__global__ void prep_c1w_kernel(const float* __restrict__ c1W, const float* __restrict__ film,
                                u16* __restrict__ c1Wt) {
  int idx = blockIdx.x * 256 + threadIdx.x;
  if (idx < 16384) {
    int j = idx & 7, l = (idx >> 3) & 63, frag = idx >> 9;
    int ks = frag >> 2, nb = frag & 3;
    int c2 = nb * 32 + (l & 31);
    int h  = l >> 5;
    int ch = 8 * (2 * ks + (j >> 2)) + h * 4 + (j & 3);
    c1Wt[idx] = f2b(film[128 + ch] * c1W[ch * HD + c2]);
  }
}

// ---- biasp[c] = c1b[c] + sum_k shift[k] * c1W[k][c] ----
__global__ void prep_bias_kernel(const float* __restrict__ c1b, const float* __restrict__ film,
                                 const float* __restrict__ c1W, float* __restrict__ biasp) {
  int t = threadIdx.x;  // 0..127
  float acc = c1b[t];
  #pragma unroll 8
  for (int k = 0; k < 128; ++k) acc = fmaf(film[k], c1W[k * HD + t], acc);
  biasp[t] = acc;
}

// ---- P[node][256] fp16, 32x32-C-layout slot order:
//      ch -> nblk=ch>>5, w=ch&31, hi=(w>>2)&1, r=(w&3)+4*(w>>3)
//      slot = side*128 + hi*64 + nblk*16 + r ----
__global__ __launch_bounds__(256) void prep_P_kernel(const float* __restrict__ h,
                                                     const u16* __restrict__ wPt,
                                                     const float* __restrict__ ib,
                                                     u16* __restrict__ P) {
  __shared__ u16 sWp[256][136];
  __shared__ float sib[HD];
  int t = threadIdx.x;
  if (t < 128) sib[t] = ib[t];
  {
    const u16* src = wPt + t * 128;
    #pragma unroll
    for (int i = 0; i < 16; ++i)
      *(uint4*)&sWp[t][i * 8] = *(const uint4*)(src + i * 8);
  }
  int wave = t >> 6, lane = t & 63, l15 = lane & 15, lg = lane >> 4;
  int node = blockIdx.x * 64 + wave * 16 + l15;
  uint4 hb[4];
  const float* hr = h + (size_t)node * HD + lg * 8;
  #pragma unroll
  for (int c = 0; c < 4; ++c) {
    float4 a = *(const float4*)(hr + c * 32);
    float4 b = *(const float4*)(hr + c * 32 + 4);
    hb[c].x = cvtpk(a.x, a.y); hb[c].y = cvtpk(a.z, a.w);
    hb[c].z = cvtpk(b.x, b.y); hb[c].w = cvtpk(b.z, b.w);
  }
  __syncthreads();
  f32x4 acc[16];
  #pragma unroll
  for (int n = 0; n < 16; ++n) acc[n] = (f32x4){0.f, 0.f, 0.f, 0.f};
  #pragma unroll
  for (int c = 0; c < 4; ++c) {
    s16x8 bF = *(const s16x8*)&hb[c];
    #pragma unroll
    for (int n = 0; n < 16; ++n) {
      s16x8 aF = *(const s16x8*)&sWp[n * 16 + l15][c * 32 + lg * 8];
      acc[n] = __builtin_amdgcn_mfma_f32_16x16x32_bf16(aF, bF, acc[n], 0, 0, 0);
    }
  }
  u16* dst = P + (size_t)node * 256;
  #pragma unroll
  for (int n = 0; n < 16; ++n) {
    int side = (n >> 3);                  // n<8 -> P_r, else P_c
    int ch = (n & 7) * 16 + lg * 4;       // semantic channel base (0..127)
    float a0 = acc[n][0], a1 = acc[n][1], a2 = acc[n][2], a3 = acc[n][3];
    if (side == 0) { a0 += sib[ch]; a1 += sib[ch + 1]; a2 += sib[ch + 2]; a3 += sib[ch + 3]; }
    int nblk = ch >> 5, w = ch & 31;
    int hi2 = (w >> 2) & 1;
    int slot = side * 128 + hi2 * 64 + nblk * 16 + 4 * (w >> 3);
    __half2 h01 = __floats2half2_rn(a0, a1);
    __half2 h23 = __floats2half2_rn(a2, a3);
    uint2 wv;
    wv.x = __builtin_bit_cast(u32, h01);
    wv.y = __builtin_bit_cast(u32, h23);
    *(uint2*)(dst + slot) = wv;
  }
}

// ---- out = pos ----
__global__ void copy_pos_kernel(const float* __restrict__ pos, float* __restrict__ out) {
  int i = blockIdx.x * 256 + threadIdx.x;
  if (i < NN * 3) out[i] = pos[i];
}

// ---- persistent fused edge kernel: 32x32 MFMA, 32 edges/wave ----
__global__ __launch_bounds__(512, 2) void edge_kernel(
    const float* __restrict__ pos,
    const float* __restrict__ edge_attr,
    const float* __restrict__ dist,
    const float* __restrict__ c2w,
    const float* __restrict__ cn_scale,
    const int*   __restrict__ eidx,
    const u16*   __restrict__ P,       // [N][256] fp16, 32x32-slot order
    const u16*   __restrict__ wadWt,   // 16 KB bf16 GEMM1 frags
    const u16*   __restrict__ c1Wt,    // 32 KB bf16 GEMM2 frags (k-permuted)
    const float* __restrict__ biasp,   // [128]
    float*       __restrict__ out)
{
  __shared__ u16   sW1[8192];    // 16 KB
  __shared__ u16   sW2[16384];   // 32 KB
  __shared__ float sC1b[HD];
  __shared__ float sC2w[HD];

  const int t    = threadIdx.x;
  const int lane = t & 63;
  const int wave = t >> 6;        // 0..7
  const int el   = lane & 31;     // edge slot within wave
  const int hi   = lane >> 5;     // 0/1: channel-half
  const int wv   = wave * 32 + el;
  const int lbase = lane * 16;    // byte base within each 1KB fragment

  if (t < HD) { sC1b[t] = biasp[t]; sC2w[t] = c2w[t]; }
  {
    const uint4* s1 = (const uint4*)wadWt;   // 1024 uint4
    uint4* d1 = (uint4*)sW1;
    #pragma unroll
    for (int i = 0; i < 2; ++i) d1[t + i * 512] = s1[t + i * 512];
    const uint4* s2 = (const uint4*)c1Wt;    // 2048 uint4
    uint4* d2 = (uint4*)sW2;
    #pragma unroll
    for (int i = 0; i < 4; ++i) d2[t + i * 512] = s2[t + i * 512];
  }

  const float cns = cn_scale[0];

  // carried state for current tile: indices, pos, packed feature frags
  int riA, ciA;
  float p0x, p0y, p0z, p1x, p1y, p1z;
  uint4 ef[4];

  // prologue for tile = blockIdx.x
  {
    int e = blockIdx.x * TB + wv;
    riA = eidx[e]; ciA = eidx[EE + e];
    p0x = pos[riA*3+0]; p0y = pos[riA*3+1]; p0z = pos[riA*3+2];
    p1x = pos[ciA*3+0]; p1y = pos[ciA*3+1]; p1z = pos[ciA*3+2];
    const float* pa_ = edge_attr + (size_t)e * 32 + hi * 8;
    const float* pd_ = dist      + (size_t)e * 32 + hi * 8;
    float4 A0 = *(const float4*)(pa_);      float4 A1 = *(const float4*)(pa_ + 4);
    float4 A2 = *(const float4*)(pa_ + 16); float4 A3 = *(const float4*)(pa_ + 20);
    float4 D0 = *(const float4*)(pd_);      float4 D1 = *(const float4*)(pd_ + 4);
    float4 D2 = *(const float4*)(pd_ + 16); float4 D3 = *(const float4*)(pd_ + 20);
    ef[0] = (uint4){cvtpk(A0.x,A0.y), cvtpk(A0.z,A0.w), cvtpk(A1.x,A1.y), cvtpk(A1.z,A1.w)};
    ef[1] = (uint4){cvtpk(A2.x,A2.y), cvtpk(A2.z,A2.w), cvtpk(A3.x,A3.y), cvtpk(A3.z,A3.w)};
    ef[2] = (uint4){cvtpk(D0.x,D0.y), cvtpk(D0.z,D0.w), cvtpk(D1.x,D1.y), cvtpk(D1.z,D1.w)};
    ef[3] = (uint4){cvtpk(D2.x,D2.y), cvtpk(D2.z,D2.w), cvtpk(D3.x,D3.y), cvtpk(D3.z,D3.w)};
  }

  __syncthreads();   // weights + consts visible

  for (int tile = blockIdx.x; tile < NTILES; tile += GRID) {
    int tn = tile + GRID; if (tn >= NTILES) tn = tile;
    int e1 = tn * TB + wv;

    // (1) next tile's indices (landed by epilogue)
    int riN = eidx[e1];
    int ciN = eidx[EE + e1];

    // (2) current tile's P gathers: 64 fp16 per side per lane (contiguous)
    uint4 pr[8], pc[8];
    {
      const u16* prp = P + (size_t)riA * 256 + hi * 64;
      const u16* pcp = P + (size_t)ciA * 256 + 128 + hi * 64;
      #pragma unroll
      for (int i = 0; i < 8; ++i) pr[i] = *(const uint4*)(prp + i * 8);
      #pragma unroll
      for (int i = 0; i < 8; ++i) pc[i] = *(const uint4*)(pcp + i * 8);
    }

    // (3) GEMM1: 4 ks x 4 nb, A from LDS (immediate offsets), B = carried ef frags
    f32x16 acc1[4];
    #pragma unroll
    for (int b = 0; b < 4; ++b)
      #pragma unroll
      for (int r = 0; r < 16; ++r) acc1[b][r] = 0.f;
    #pragma unroll
    for (int ks = 0; ks < 4; ++ks) {
      s16x8 bF = __builtin_bit_cast(s16x8, ef[ks]);
      #pragma unroll
      for (int b = 0; b < 4; ++b) {
        s16x8 aF = *(const s16x8*)((const char*)sW1 + (ks * 4 + b) * 1024 + lbase);
        acc1[b] = __builtin_amdgcn_mfma_f32_32x32x16_bf16(aF, bF, acc1[b], 0, 0, 0);
      }
    }

    // (4) ps = P_r + P_c (packed fp16 adds)
    uint4 ps[8];
    #pragma unroll
    for (int i = 0; i < 8; ++i) {
      const __half2* a2 = (const __half2*)&pr[i];
      const __half2* b2 = (const __half2*)&pc[i];
      __half2 r0 = __hadd2(a2[0], b2[0]);
      __half2 r1 = __hadd2(a2[1], b2[1]);
      __half2 r2 = __hadd2(a2[2], b2[2]);
      __half2 r3 = __hadd2(a2[3], b2[3]);
      ps[i].x = __builtin_bit_cast(u32, r0);
      ps[i].y = __builtin_bit_cast(u32, r1);
      ps[i].z = __builtin_bit_cast(u32, r2);
      ps[i].w = __builtin_bit_cast(u32, r3);
    }

    // (5) x = Q + ps; LN stats (4-way partials; lane holds 64 of 128 channels)
    float xf[4][16];
    float s0=0.f,s1=0.f,s2=0.f,s3=0.f, q0=0.f,q1=0.f,q2=0.f,q3=0.f;
    #pragma unroll
    for (int b = 0; b < 4; ++b) {
      #pragma unroll
      for (int k = 0; k < 8; ++k) {
        __half2 hv = ((const __half2*)&ps[2*b + (k>>2)])[k & 3];
        float2 f = __half22float2(hv);
        float v0 = acc1[b][2*k]     + f.x;
        float v1 = acc1[b][2*k + 1] + f.y;
        xf[b][2*k] = v0; xf[b][2*k+1] = v1;
        if (k & 1) { s1 += v0 + v1; q1 = fmaf(v0,v0,q1); q1 = fmaf(v1,v1,q1); }
        else       { s0 += v0 + v1; q0 = fmaf(v0,v0,q0); q0 = fmaf(v1,v1,q0); }
      }
    }
    float sum = (s0 + s1) + (s2 + s3);
    float sq  = (q0 + q1) + (q2 + q3);
    sum += __shfl_xor(sum, 32);
    sq  += __shfl_xor(sq,  32);
    float mean = sum * (1.f / 128.f);
    float var  = sq  * (1.f / 128.f) - mean * mean;
    float LA = rsqrtf(var + 1e-6f);
    float LB = -mean * LA;

    // (6) x-hat -> bf16 pairs; word layout = GEMM2 B-frags (k-permuted weights)
    u32 xb[4][8];
    #pragma unroll
    for (int b = 0; b < 4; ++b)
      #pragma unroll
      for (int w = 0; w < 8; ++w) {
        float y0 = fmaf(xf[b][2*w],   LA, LB);
        float y1 = fmaf(xf[b][2*w+1], LA, LB);
        xb[b][w] = cvtpk(y0, y1);
      }

    // (7) GEMM2: 8 ks x 4 nb; B-frag = xb[ks>>1][4*(ks&1)..+3]
    f32x16 acc2[4];
    #pragma unroll
    for (int b = 0; b < 4; ++b)
      #pragma unroll
      for (int r = 0; r < 16; ++r) acc2[b][r] = 0.f;
    #pragma unroll
    for (int ks = 0; ks < 8; ++ks) {
      int bb = ks >> 1, off = (ks & 1) * 4;
      u32x4 xw = { xb[bb][off], xb[bb][off+1], xb[bb][off+2], xb[bb][off+3] };
      s16x8 xF = __builtin_bit_cast(s16x8, xw);
      #pragma unroll
      for (int nb = 0; nb < 4; ++nb) {
        s16x8 aF = *(const s16x8*)((const char*)sW2 + (ks * 4 + nb) * 1024 + lbase);
        acc2[nb] = __builtin_amdgcn_mfma_f32_32x32x16_bf16(aF, xF, acc2[nb], 0, 0, 0);
      }
    }

    // (8) silu -> dot(c2W); channel c2 = b*32 + 8*rg + 4*hi + i for reg r = rg*4+i
    float z0=0.f, z1=0.f, z2=0.f, z3=0.f;
    #pragma unroll
    for (int b = 0; b < 4; ++b) {
      #pragma unroll
      for (int rg = 0; rg < 4; ++rg) {
        int base = b * 32 + 8 * rg + 4 * hi;
        f32x4 cb4 = *(const f32x4*)&sC1b[base];
        f32x4 cw4 = *(const f32x4*)&sC2w[base];
        float y0 = acc2[b][rg*4+0] + cb4[0];
        float y1 = acc2[b][rg*4+1] + cb4[1];
        float y2 = acc2[b][rg*4+2] + cb4[2];
        float y3 = acc2[b][rg*4+3] + cb4[3];
        z0 = fmaf(y0 * __builtin_amdgcn_rcpf(1.f + __expf(-y0)), cw4[0], z0);
        z1 = fmaf(y1 * __builtin_amdgcn_rcpf(1.f + __expf(-y1)), cw4[1], z1);
        z2 = fmaf(y2 * __builtin_amdgcn_rcpf(1.f + __expf(-y2)), cw4[2], z2);
        z3 = fmaf(y3 * __builtin_amdgcn_rcpf(1.f + __expf(-y3)), cw4[3], z3);
      }
    }
    float z = (z0 + z1) + (z2 + z3);
    z += __shfl_xor(z, 32);

    // (9) next tile: attr/dist + pos loads, pack frags
    float4 A0, A1, A2, A3, D0, D1, D2, D3;
    {
      const float* pa_ = edge_attr + (size_t)e1 * 32 + hi * 8;
      const float* pd_ = dist      + (size_t)e1 * 32 + hi * 8;
      A0 = *(const float4*)(pa_);      A1 = *(const float4*)(pa_ + 4);
      A2 = *(const float4*)(pa_ + 16); A3 = *(const float4*)(pa_ + 20);
      D0 = *(const float4*)(pd_);      D1 = *(const float4*)(pd_ + 4);
      D2 = *(const float4*)(pd_ + 16); D3 = *(const float4*)(pd_ + 20);
    }
    float n0x = pos[riN*3+0], n0y = pos[riN*3+1], n0z = pos[riN*3+2];
    float n1x = pos[ciN*3+0], n1y = pos[ciN*3+1], n1z = pos[ciN*3+2];

    // (10) tanh -> scatter (lo lane: dims 0,1; hi lane: dim 2)
    {
      float zc = fminf(fmaxf(z, -15.f), 15.f);
      float ez = __expf(2.f * zc);
      float inv = (ez - 1.f) * __builtin_amdgcn_rcpf(ez + 1.f);
      float dx = p0x - p1x, dy = p0y - p1y, dz = p0z - p1z;
      float nrm = sqrtf(fmaf(dx, dx, fmaf(dy, dy, dz * dz)));
      float sc  = cns * inv * __builtin_amdgcn_rcpf(fmaxf(nrm, 1e-8f));
      if (hi == 0) {
        atomicAdd(out + (size_t)riA * 3 + 0, dx * sc);
        atomicAdd(out + (size_t)riA * 3 + 1, dy * sc);
      } else {
        atomicAdd(out + (size_t)riA * 3 + 2, dz * sc);
      }
    }

    // (11) rotate carries
    riA = riN; ciA = ciN;
    p0x = n0x; p0y = n0y; p0z = n0z; p1x = n1x; p1y = n1y; p1z = n1z;
    ef[0] = (uint4){cvtpk(A0.x,A0.y), cvtpk(A0.z,A0.w), cvtpk(A1.x,A1.y), cvtpk(A1.z,A1.w)};
    ef[1] = (uint4){cvtpk(A2.x,A2.y), cvtpk(A2.z,A2.w), cvtpk(A3.x,A3.y), cvtpk(A3.z,A3.w)};
    ef[2] = (uint4){cvtpk(D0.x,D0.y), cvtpk(D0.z,D0.w), cvtpk(D1.x,D1.y), cvtpk(D1.z,D1.w)};
    ef[3] = (uint4){cvtpk(D2.x,D2.y), cvtpk(D2.z,D2.w), cvtpk(D3.x,D3.y), cvtpk(D3.z,D3.w)};
  }
}

extern "C" void kernel_launch(void* const* d_in, const int* in_sizes, int n_in,
                              void* d_out, int out_size, void* d_ws, size_t ws_size,
                              hipStream_t stream) {
  const float* h         = (const float*)d_in[0];
  const float* pos       = (const float*)d_in[1];
  const float* edge_attr = (const float*)d_in[2];
  const float* dist      = (const float*)d_in[3];
  const float* te        = (const float*)d_in[4];
  const float* tW        = (const float*)d_in[5];
  const float* tb        = (const float*)d_in[6];
  const float* iW        = (const float*)d_in[7];
  const float* ib        = (const float*)d_in[8];
  const float* c1W       = (const float*)d_in[9];
  const float* c1b       = (const float*)d_in[10];
  const float* c2W       = (const float*)d_in[11];
  const float* cn        = (const float*)d_in[12];
  const int*   eidx      = (const int*)d_in[13];
  float* out = (float*)d_out;

  char* ws = (char*)d_ws;
  u16*   P      = (u16*)(ws);                    // 40000*256*2 = 20,480,000 B (fp16)
  u16*   wPt    = (u16*)(ws + 20480000);         // 65,536 B
  u16*   wadWt  = (u16*)(ws + 20545536);         // 16,384 B
  u16*   c1Wt   = (u16*)(ws + 20561920);         // 32,768 B
  float* film   = (float*)(ws + 20594688);       // 1,024 B
  float* biasp  = (float*)(ws + 20595712);       // 512 B

  hipLaunchKernelGGL(prep_film_kernel, dim3(1),   dim3(256), 0, stream, te, tW, tb, film);
  hipLaunchKernelGGL(prep_wpt_kernel,  dim3(128), dim3(256), 0, stream, iW, wPt);
  hipLaunchKernelGGL(prep_ad_kernel,   dim3(32),  dim3(256), 0, stream, iW, wadWt);
  hipLaunchKernelGGL(prep_c1w_kernel,  dim3(64),  dim3(256), 0, stream, c1W, film, c1Wt);
  hipLaunchKernelGGL(prep_bias_kernel, dim3(1),   dim3(128), 0, stream, c1b, film, c1W, biasp);
  hipLaunchKernelGGL(prep_P_kernel,    dim3(625), dim3(256), 0, stream, h, wPt, ib, P);
  hipLaunchKernelGGL(copy_pos_kernel,  dim3(469), dim3(256), 0, stream, pos, out);
  hipLaunchKernelGGL(edge_kernel,      dim3(GRID), dim3(512), 0, stream,
                     pos, edge_attr, dist, c2W, cn, eidx,
                     P, wadWt, c1Wt, biasp, out);
}

// Round 17
// 119.225 us; speedup vs baseline: 3.2623x; 1.2172x over previous
//
#include <hip/hip_runtime.h>
#include <hip/hip_bf16.h>
#include <stdint.h>

#define NN 40000
#define EE 640000
#define HD 128
#define TDIM 128
#define TB 128
#define NTILES (EE / TB)   // 5000
#define GRID 512           // persistent: 2 blocks/CU, 16 waves/CU

typedef short  s16x8 __attribute__((ext_vector_type(8)));
typedef float  f32x4 __attribute__((ext_vector_type(4)));
typedef unsigned int u32x4 __attribute__((ext_vector_type(4)));
typedef unsigned short u16;
typedef unsigned int   u32;

__device__ __forceinline__ u32 cvtpk(float lo, float hi) {
  u32 r; asm("v_cvt_pk_bf16_f32 %0, %1, %2" : "=v"(r) : "v"(lo), "v"(hi)); return r;
}
__device__ __forceinline__ float b2f_lo(u32 w){ union{u32 u; float f;} x; x.u = w << 16; return x.f; }
__device__ __forceinline__ float b2f_hi(u32 w){ union{u32 u; float f;} x; x.u = w & 0xffff0000u; return x.f; }
__device__ __forceinline__ u16 f2b(float f) {
  union { float f; u32 u; } x; x.f = f;
  u32 r = x.u + 0x7fffu + ((x.u >> 16) & 1u);
  return (u16)(r >> 16);
}

// ---- launch 1: FiLM params: film[0:128]=shift, film[128:256]=1+scale ----
__global__ void prep_film_kernel(const float* __restrict__ te, const float* __restrict__ tW,
                                 const float* __restrict__ tb, float* __restrict__ film) {
  __shared__ float s[TDIM];
  int t = threadIdx.x;
  if (t < TDIM) { float v = te[t]; s[t] = v * __builtin_amdgcn_rcpf(1.f + __expf(-v)); }
  __syncthreads();
  float acc = tb[t];
  #pragma unroll 8
  for (int k = 0; k < TDIM; ++k) acc = fmaf(s[k], tW[k * 256 + t], acc);
  film[t] = (t >= 128) ? (1.f + acc) : acc;
}

// ---- launch 2 (fused): wPt | wadWt | c1Wt | biasp, partitioned by blockIdx ----
//  blocks [0,128):   wPt[256][128]: wPt[c][k] = iW[(c>>7)*128 + k][c&127]
//  blocks [128,160): GEMM1 weights fragment-ordered:
//                    idx = ks*4096+lg*1024+n*128+l15*8+j ; iW[256+ks*32+lg*8+j][n*16+l15]
//  blocks [160,224): GEMM2 weights, k-permuted + fragment-ordered:
//                    ch = (2*kq+(j>>2))*16+lg*4+(j&3) ; (1+scale[ch])*c1W[ch][n*16+l15]
//  block 224:        biasp[c] = c1b[c] + sum_k shift[k]*c1W[k][c]
__global__ void prep_weights_kernel(const float* __restrict__ iW,
                                    const float* __restrict__ c1W,
                                    const float* __restrict__ film,
                                    const float* __restrict__ c1b,
                                    u16* __restrict__ wPt,
                                    u16* __restrict__ wadWt,
                                    u16* __restrict__ c1Wt,
                                    float* __restrict__ biasp) {
  int b = blockIdx.x, t = threadIdx.x;
  if (b < 128) {
    int idx = b * 256 + t;                 // < 32768
    int c = idx >> 7, k = idx & 127;
    wPt[idx] = f2b(iW[((c >> 7) * 128 + k) * HD + (c & 127)]);
  } else if (b < 160) {
    int idx = (b - 128) * 256 + t;         // < 8192
    int j = idx & 7, l15 = (idx >> 3) & 15, n = (idx >> 7) & 7, lg = (idx >> 10) & 3, ks = idx >> 12;
    int row = n * 16 + l15;
    int k = ks * 32 + lg * 8 + j;
    wadWt[idx] = f2b(iW[(256 + k) * HD + row]);
  } else if (b < 224) {
    int idx = (b - 160) * 256 + t;         // < 16384
    int j = idx & 7, l15 = (idx >> 3) & 15, n = (idx >> 7) & 7, lg = (idx >> 10) & 3, kq = idx >> 12;
    int row = n * 16 + l15;
    int ch = (kq * 2 + (j >> 2)) * 16 + lg * 4 + (j & 3);
    c1Wt[idx] = f2b(film[128 + ch] * c1W[ch * HD + row]);
  } else if (t < 128) {
    float acc = c1b[t];
    #pragma unroll 8
    for (int k = 0; k < 128; ++k) acc = fmaf(film[k], c1W[k * HD + t], acc);
    biasp[t] = acc;
  }
}

// ---- launch 3: P[node][256] bf16 fragment-permuted + copy pos->out slice ----
__global__ __launch_bounds__(256) void prep_P_kernel(const float* __restrict__ h,
                                                     const u16* __restrict__ wPt,
                                                     const float* __restrict__ ib,
                                                     const float* __restrict__ pos,
                                                     u16* __restrict__ P,
                                                     float* __restrict__ out) {
  __shared__ u16 sWp[256][136];
  __shared__ float sib[HD];
  int t = threadIdx.x;
  // folded copy_pos: 625 blocks x 192 floats = 120000 = NN*3
  {
    int ci = blockIdx.x * 192 + t;
    if (t < 192) out[ci] = pos[ci];
  }
  if (t < 128) sib[t] = ib[t];
  {
    const u16* src = wPt + t * 128;
    #pragma unroll
    for (int i = 0; i < 16; ++i)
      *(uint4*)&sWp[t][i * 8] = *(const uint4*)(src + i * 8);
  }
  int wave = t >> 6, lane = t & 63, l15 = lane & 15, lg = lane >> 4;
  int node = blockIdx.x * 64 + wave * 16 + l15;
  uint4 hb[4];
  const float* hr = h + (size_t)node * HD + lg * 8;
  #pragma unroll
  for (int c = 0; c < 4; ++c) {
    float4 a = *(const float4*)(hr + c * 32);
    float4 b = *(const float4*)(hr + c * 32 + 4);
    hb[c].x = cvtpk(a.x, a.y); hb[c].y = cvtpk(a.z, a.w);
    hb[c].z = cvtpk(b.x, b.y); hb[c].w = cvtpk(b.z, b.w);
  }
  __syncthreads();
  f32x4 acc[16];
  #pragma unroll
  for (int n = 0; n < 16; ++n) acc[n] = (f32x4){0.f, 0.f, 0.f, 0.f};
  #pragma unroll
  for (int c = 0; c < 4; ++c) {
    s16x8 bF = *(const s16x8*)&hb[c];
    #pragma unroll
    for (int n = 0; n < 16; ++n) {
      s16x8 aF = *(const s16x8*)&sWp[n * 16 + l15][c * 32 + lg * 8];
      acc[n] = __builtin_amdgcn_mfma_f32_16x16x32_bf16(aF, bF, acc[n], 0, 0, 0);
    }
  }
  u16* dst = P + (size_t)node * 256;
  #pragma unroll
  for (int n = 0; n < 16; ++n) {
    int cb = n * 16 + lg * 4;
    float a0 = acc[n][0], a1 = acc[n][1], a2 = acc[n][2], a3 = acc[n][3];
    if (n < 8) { a0 += sib[cb]; a1 += sib[cb + 1]; a2 += sib[cb + 2]; a3 += sib[cb + 3]; }
    int slot = (n < 8) ? (lg * 32 + n * 4) : (128 + lg * 32 + (n - 8) * 4);
    uint2 wv; wv.x = cvtpk(a0, a1); wv.y = cvtpk(a2, a3);
    *(uint2*)(dst + slot) = wv;
  }
}

// ---- small prefetch state ----
struct PfS {
  int ri, ci;
  float4 a0, a1, d0, d1;
  float p0x, p0y, p0z, p1x, p1y, p1z;
};

// ---- launch 4: persistent fused edge kernel (R13 verbatim) ----
__global__ __launch_bounds__(512, 4) void edge_kernel(
    const float* __restrict__ pos,
    const float* __restrict__ edge_attr,
    const float* __restrict__ dist,
    const float* __restrict__ c2w,
    const float* __restrict__ cn_scale,
    const int*   __restrict__ eidx,
    const u16*   __restrict__ P,       // [N][256] bf16, fragment-permuted
    const u16*   __restrict__ wadWt,   // [8192]  fragment-ordered GEMM1 weights
    const u16*   __restrict__ c1Wt,    // [16384] fragment-ordered, k-permuted GEMM2 weights
    const float* __restrict__ biasp,   // [128]
    float*       __restrict__ out)
{
  __shared__ u16   sW1[8192];    // 16 KB
  __shared__ u16   sW2[16384];   // 32 KB
  __shared__ float sC1b[HD];
  __shared__ float sC2w[HD];

  const int t    = threadIdx.x;
  const int lane = t & 63;
  const int wave = t >> 6;        // 0..7
  const int l15  = lane & 15;
  const int lg   = lane >> 4;
  const int wv   = wave * 16 + l15;   // edge offset in tile, 0..127

  if (t < HD) { sC1b[t] = biasp[t]; sC2w[t] = c2w[t]; }
  {
    const uint4* s1 = (const uint4*)wadWt;   // 1024 uint4
    uint4* d1 = (uint4*)sW1;
    #pragma unroll
    for (int i = 0; i < 2; ++i) d1[t + i * 512] = s1[t + i * 512];
    const uint4* s2 = (const uint4*)c1Wt;    // 2048 uint4
    uint4* d2 = (uint4*)sW2;
    #pragma unroll
    for (int i = 0; i < 4; ++i) d2[t + i * 512] = s2[t + i * 512];
  }

  const float cns = cn_scale[0];
  const int bbase = lg * 2048 + l15 * 16;   // byte base within each 8KB k-panel

  auto pf_idx_ad = [&](PfS& p, int tile) {
    int e = tile * TB + wv;
    p.ri = eidx[e];
    p.ci = eidx[EE + e];
    const float* pa = edge_attr + (size_t)e * 32 + lg * 8;
    const float* pd = dist      + (size_t)e * 32 + lg * 8;
    p.a0 = *(const float4*)(pa); p.a1 = *(const float4*)(pa + 4);
    p.d0 = *(const float4*)(pd); p.d1 = *(const float4*)(pd + 4);
  };
  auto pf_pos = [&](PfS& p) {
    p.p0x = pos[p.ri * 3 + 0]; p.p0y = pos[p.ri * 3 + 1]; p.p0z = pos[p.ri * 3 + 2];
    p.p1x = pos[p.ci * 3 + 0]; p.p1y = pos[p.ci * 3 + 1]; p.p1z = pos[p.ci * 3 + 2];
  };

  PfS A, B;
  pf_idx_ad(A, blockIdx.x);
  pf_pos(A);

  // prologue: P gathers for the first tile
  uint4 pra0, pra1, pra2, pra3, pca0, pca1, pca2, pca3;
  {
    const u16* pr = P + (size_t)A.ri * 256 + lg * 32;
    const u16* pc = P + (size_t)A.ci * 256 + 128 + lg * 32;
    pra0 = *(const uint4*)(pr);      pra1 = *(const uint4*)(pr + 8);
    pra2 = *(const uint4*)(pr + 16); pra3 = *(const uint4*)(pr + 24);
    pca0 = *(const uint4*)(pc);      pca1 = *(const uint4*)(pc + 8);
    pca2 = *(const uint4*)(pc + 16); pca3 = *(const uint4*)(pc + 24);
  }

  __syncthreads();   // only barrier: weights + consts visible

  for (int tile = blockIdx.x; tile < NTILES; tile += GRID) {
    int tn = tile + GRID; if (tn >= NTILES) tn = tile;

    // (1) next tile's independent loads — in flight across this tile
    pf_idx_ad(B, tn);

    // (2) GEMM1: Q = [attr|dist] @ iW_ad, all-immediate-offset LDS reads
    uint4 ef0, ef1;
    ef0.x = cvtpk(A.a0.x, A.a0.y); ef0.y = cvtpk(A.a0.z, A.a0.w);
    ef0.z = cvtpk(A.a1.x, A.a1.y); ef0.w = cvtpk(A.a1.z, A.a1.w);
    ef1.x = cvtpk(A.d0.x, A.d0.y); ef1.y = cvtpk(A.d0.z, A.d0.w);
    ef1.z = cvtpk(A.d1.x, A.d1.y); ef1.w = cvtpk(A.d1.z, A.d1.w);

    f32x4 acc[8];
    #pragma unroll
    for (int n = 0; n < 8; ++n) acc[n] = (f32x4){0.f, 0.f, 0.f, 0.f};
    #pragma unroll
    for (int ks = 0; ks < 2; ++ks) {
      s16x8 bF = (ks == 0) ? *(const s16x8*)&ef0 : *(const s16x8*)&ef1;
      #pragma unroll
      for (int n = 0; n < 8; ++n) {
        s16x8 aF = *(const s16x8*)((const char*)sW1 + ks * 8192 + bbase + n * 256);
        acc[n] = __builtin_amdgcn_mfma_f32_16x16x32_bf16(aF, bF, acc[n], 0, 0, 0);
      }
    }

    // (3) x = Q + P_r + P_c; LN stats with 4-way partial accumulators
    float x[8][4];
    float s0=0.f,s1=0.f,s2=0.f,s3=0.f, q0=0.f,q1=0.f,q2=0.f,q3=0.f;
    #pragma unroll
    for (int i = 0; i < 4; ++i) {
      uint4 pa = (i == 0) ? pra0 : (i == 1) ? pra1 : (i == 2) ? pra2 : pra3;
      uint4 pc = (i == 0) ? pca0 : (i == 1) ? pca1 : (i == 2) ? pca2 : pca3;
      float v0 = acc[2*i][0] + b2f_lo(pa.x) + b2f_lo(pc.x);
      float v1 = acc[2*i][1] + b2f_hi(pa.x) + b2f_hi(pc.x);
      float v2 = acc[2*i][2] + b2f_lo(pa.y) + b2f_lo(pc.y);
      float v3 = acc[2*i][3] + b2f_hi(pa.y) + b2f_hi(pc.y);
      float v4 = acc[2*i+1][0] + b2f_lo(pa.z) + b2f_lo(pc.z);
      float v5 = acc[2*i+1][1] + b2f_hi(pa.z) + b2f_hi(pc.z);
      float v6 = acc[2*i+1][2] + b2f_lo(pa.w) + b2f_lo(pc.w);
      float v7 = acc[2*i+1][3] + b2f_hi(pa.w) + b2f_hi(pc.w);
      x[2*i][0]=v0; x[2*i][1]=v1; x[2*i][2]=v2; x[2*i][3]=v3;
      x[2*i+1][0]=v4; x[2*i+1][1]=v5; x[2*i+1][2]=v6; x[2*i+1][3]=v7;
      s0 += v0 + v4;  s1 += v1 + v5;  s2 += v2 + v6;  s3 += v3 + v7;
      q0 = fmaf(v0,v0,q0); q1 = fmaf(v1,v1,q1); q2 = fmaf(v2,v2,q2); q3 = fmaf(v3,v3,q3);
      q0 = fmaf(v4,v4,q0); q1 = fmaf(v5,v5,q1); q2 = fmaf(v6,v6,q2); q3 = fmaf(v7,v7,q3);
    }
    float sum = (s0 + s1) + (s2 + s3);
    float sq  = (q0 + q1) + (q2 + q3);
    sum += __shfl_xor(sum, 16); sum += __shfl_xor(sum, 32);
    sq  += __shfl_xor(sq,  16); sq  += __shfl_xor(sq,  32);
    float mean = sum * (1.f / 128.f);
    float var  = sq  * (1.f / 128.f) - mean * mean;
    float LA = rsqrtf(var + 1e-6f);
    float LB = -mean * LA;

    union { uint2 u2[8]; u32 w[16]; } xb;
    #pragma unroll
    for (int n = 0; n < 8; ++n) {
      float y0 = fmaf(x[n][0], LA, LB);
      float y1 = fmaf(x[n][1], LA, LB);
      float y2 = fmaf(x[n][2], LA, LB);
      float y3 = fmaf(x[n][3], LA, LB);
      xb.u2[n].x = cvtpk(y0, y1);
      xb.u2[n].y = cvtpk(y2, y3);
    }

    // (4) GEMM2: B from registers, A via immediate-offset LDS
    f32x4 acc2[8];
    #pragma unroll
    for (int n = 0; n < 8; ++n) acc2[n] = (f32x4){0.f, 0.f, 0.f, 0.f};
    #pragma unroll
    for (int kq = 0; kq < 4; ++kq) {
      u32x4 xw = { xb.w[4*kq], xb.w[4*kq+1], xb.w[4*kq+2], xb.w[4*kq+3] };
      s16x8 xF = __builtin_bit_cast(s16x8, xw);
      #pragma unroll
      for (int n = 0; n < 8; ++n) {
        s16x8 aF = *(const s16x8*)((const char*)sW2 + kq * 8192 + bbase + n * 256);
        acc2[n] = __builtin_amdgcn_mfma_f32_16x16x32_bf16(aF, xF, acc2[n], 0, 0, 0);
      }
    }

    // (5) silu -> dot(c2W) with 4-way partial chains
    float z0=0.f, z1=0.f, z2=0.f, z3=0.f;
    #pragma unroll
    for (int n = 0; n < 8; ++n) {
      int cb = n * 16 + lg * 4;
      f32x4 cb4 = *(const f32x4*)&sC1b[cb];
      f32x4 cw4 = *(const f32x4*)&sC2w[cb];
      float y0 = acc2[n][0] + cb4[0];
      float y1 = acc2[n][1] + cb4[1];
      float y2 = acc2[n][2] + cb4[2];
      float y3 = acc2[n][3] + cb4[3];
      z0 = fmaf(y0 * __builtin_amdgcn_rcpf(1.f + __expf(-y0)), cw4[0], z0);
      z1 = fmaf(y1 * __builtin_amdgcn_rcpf(1.f + __expf(-y1)), cw4[1], z1);
      z2 = fmaf(y2 * __builtin_amdgcn_rcpf(1.f + __expf(-y2)), cw4[2], z2);
      z3 = fmaf(y3 * __builtin_amdgcn_rcpf(1.f + __expf(-y3)), cw4[3], z3);
    }
    float z = (z0 + z1) + (z2 + z3);
    z += __shfl_xor(z, 16); z += __shfl_xor(z, 32);

    // (6) depth-1 prefetch: next tile's pos + P rows
    pf_pos(B);
    uint4 qra0, qra1, qra2, qra3, qca0, qca1, qca2, qca3;
    {
      const u16* pr = P + (size_t)B.ri * 256 + lg * 32;
      const u16* pc = P + (size_t)B.ci * 256 + 128 + lg * 32;
      qra0 = *(const uint4*)(pr);      qra1 = *(const uint4*)(pr + 8);
      qra2 = *(const uint4*)(pr + 16); qra3 = *(const uint4*)(pr + 24);
      qca0 = *(const uint4*)(pc);      qca1 = *(const uint4*)(pc + 8);
      qca2 = *(const uint4*)(pc + 16); qca3 = *(const uint4*)(pc + 24);
    }

    // (7) tanh -> scatter
    if (lg < 3) {
      float zc = fminf(fmaxf(z, -15.f), 15.f);
      float ez = __expf(2.f * zc);
      float inv = (ez - 1.f) * __builtin_amdgcn_rcpf(ez + 1.f);
      float dx = A.p0x - A.p1x, dy = A.p0y - A.p1y, dz = A.p0z - A.p1z;
      float nrm = sqrtf(fmaf(dx, dx, fmaf(dy, dy, dz * dz)));
      float sc  = cns * inv * __builtin_amdgcn_rcpf(fmaxf(nrm, 1e-8f));
      float d   = (lg == 0) ? dx : ((lg == 1) ? dy : dz);
      atomicAdd(out + (size_t)A.ri * 3 + lg, d * sc);
    }

    A = B;
    pra0 = qra0; pra1 = qra1; pra2 = qra2; pra3 = qra3;
    pca0 = qca0; pca1 = qca1; pca2 = qca2; pca3 = qca3;
  }
}

extern "C" void kernel_launch(void* const* d_in, const int* in_sizes, int n_in,
                              void* d_out, int out_size, void* d_ws, size_t ws_size,
                              hipStream_t stream) {
  const float* h         = (const float*)d_in[0];
  const float* pos       = (const float*)d_in[1];
  const float* edge_attr = (const float*)d_in[2];
  const float* dist      = (const float*)d_in[3];
  const float* te        = (const float*)d_in[4];
  const float* tW        = (const float*)d_in[5];
  const float* tb        = (const float*)d_in[6];
  const float* iW        = (const float*)d_in[7];
  const float* ib        = (const float*)d_in[8];
  const float* c1W       = (const float*)d_in[9];
  const float* c1b       = (const float*)d_in[10];
  const float* c2W       = (const float*)d_in[11];
  const float* cn        = (const float*)d_in[12];
  const int*   eidx      = (const int*)d_in[13];
  float* out = (float*)d_out;

  char* ws = (char*)d_ws;
  u16*   P      = (u16*)(ws);                    // 40000*256*2 = 20,480,000 B
  u16*   wPt    = (u16*)(ws + 20480000);         // 65,536 B
  u16*   wadWt  = (u16*)(ws + 20545536);         // 16,384 B
  u16*   c1Wt   = (u16*)(ws + 20561920);         // 32,768 B
  float* film   = (float*)(ws + 20594688);       // 1,024 B
  float* biasp  = (float*)(ws + 20595712);       // 512 B

  hipLaunchKernelGGL(prep_film_kernel,    dim3(1),    dim3(256), 0, stream, te, tW, tb, film);
  hipLaunchKernelGGL(prep_weights_kernel, dim3(225),  dim3(256), 0, stream,
                     iW, c1W, film, c1b, wPt, wadWt, c1Wt, biasp);
  hipLaunchKernelGGL(prep_P_kernel,       dim3(625),  dim3(256), 0, stream,
                     h, wPt, ib, pos, P, out);
  hipLaunchKernelGGL(edge_kernel,         dim3(GRID), dim3(512), 0, stream,
                     pos, edge_attr, dist, c2W, cn, eidx,
                     P, wadWt, c1Wt, biasp, out);
}

// Round 18
// 99.742 us; speedup vs baseline: 3.8995x; 1.1953x over previous
//
#include <hip/hip_runtime.h>
#include <hip/hip_bf16.h>
#include <stdint.h>

#define NN 40000
#define EE 640000
#define HD 128
#define TDIM 128
#define TB 128
#define NTILES (EE / TB)   // 5000
#define GRID 512           // persistent: 2 blocks/CU, 16 waves/CU

typedef short  s16x8 __attribute__((ext_vector_type(8)));
typedef float  f32x2 __attribute__((ext_vector_type(2)));
typedef float  f32x4 __attribute__((ext_vector_type(4)));
typedef unsigned int u32x4 __attribute__((ext_vector_type(4)));
typedef unsigned short u16;
typedef unsigned int   u32;

#define PSCL 8.0f        // P stored x8 in fp8 e4m3
#define PDSC 0.125f      // descale on unpack

__device__ __forceinline__ u32 cvtpk(float lo, float hi) {
  u32 r; asm("v_cvt_pk_bf16_f32 %0, %1, %2" : "=v"(r) : "v"(lo), "v"(hi)); return r;
}
__device__ __forceinline__ u16 f2b(float f) {
  union { float f; u32 u; } x; x.f = f;
  u32 r = x.u + 0x7fffu + ((x.u >> 16) & 1u);
  return (u16)(r >> 16);
}

// ---- launch 1: FiLM params: film[0:128]=shift, film[128:256]=1+scale ----
__global__ void prep_film_kernel(const float* __restrict__ te, const float* __restrict__ tW,
                                 const float* __restrict__ tb, float* __restrict__ film) {
  __shared__ float s[TDIM];
  int t = threadIdx.x;
  if (t < TDIM) { float v = te[t]; s[t] = v * __builtin_amdgcn_rcpf(1.f + __expf(-v)); }
  __syncthreads();
  float acc = tb[t];
  #pragma unroll 8
  for (int k = 0; k < TDIM; ++k) acc = fmaf(s[k], tW[k * 256 + t], acc);
  film[t] = (t >= 128) ? (1.f + acc) : acc;
}

// ---- launch 2 (fused): wPt | wadWt | c1Wt | biasp, partitioned by blockIdx ----
__global__ void prep_weights_kernel(const float* __restrict__ iW,
                                    const float* __restrict__ c1W,
                                    const float* __restrict__ film,
                                    const float* __restrict__ c1b,
                                    u16* __restrict__ wPt,
                                    u16* __restrict__ wadWt,
                                    u16* __restrict__ c1Wt,
                                    float* __restrict__ biasp) {
  int b = blockIdx.x, t = threadIdx.x;
  if (b < 128) {
    int idx = b * 256 + t;                 // < 32768
    int c = idx >> 7, k = idx & 127;
    wPt[idx] = f2b(iW[((c >> 7) * 128 + k) * HD + (c & 127)]);
  } else if (b < 160) {
    int idx = (b - 128) * 256 + t;         // < 8192
    int j = idx & 7, l15 = (idx >> 3) & 15, n = (idx >> 7) & 7, lg = (idx >> 10) & 3, ks = idx >> 12;
    int row = n * 16 + l15;
    int k = ks * 32 + lg * 8 + j;
    wadWt[idx] = f2b(iW[(256 + k) * HD + row]);
  } else if (b < 224) {
    int idx = (b - 160) * 256 + t;         // < 16384
    int j = idx & 7, l15 = (idx >> 3) & 15, n = (idx >> 7) & 7, lg = (idx >> 10) & 3, kq = idx >> 12;
    int row = n * 16 + l15;
    int ch = (kq * 2 + (j >> 2)) * 16 + lg * 4 + (j & 3);
    c1Wt[idx] = f2b(film[128 + ch] * c1W[ch * HD + row]);
  } else if (t < 128) {
    float acc = c1b[t];
    #pragma unroll 8
    for (int k = 0; k < 128; ++k) acc = fmaf(film[k], c1W[k * HD + t], acc);
    biasp[t] = acc;
  }
}

// ---- launch 3: P[node] = 64 u32 words of fp8 (x8), fragment-permuted; + pos copy ----
//      word(side,lg,n) = side*32 + lg*8 + n holds channels {n*16+lg*4 + 0..3} of that side
__global__ __launch_bounds__(256) void prep_P_kernel(const float* __restrict__ h,
                                                     const u16* __restrict__ wPt,
                                                     const float* __restrict__ ib,
                                                     const float* __restrict__ pos,
                                                     u32* __restrict__ P,
                                                     float* __restrict__ out) {
  __shared__ u16 sWp[256][136];
  __shared__ float sib[HD];
  int t = threadIdx.x;
  {
    int ci = blockIdx.x * 192 + t;
    if (t < 192) out[ci] = pos[ci];
  }
  if (t < 128) sib[t] = ib[t];
  {
    const u16* src = wPt + t * 128;
    #pragma unroll
    for (int i = 0; i < 16; ++i)
      *(uint4*)&sWp[t][i * 8] = *(const uint4*)(src + i * 8);
  }
  int wave = t >> 6, lane = t & 63, l15 = lane & 15, lg = lane >> 4;
  int node = blockIdx.x * 64 + wave * 16 + l15;
  uint4 hb[4];
  const float* hr = h + (size_t)node * HD + lg * 8;
  #pragma unroll
  for (int c = 0; c < 4; ++c) {
    float4 a = *(const float4*)(hr + c * 32);
    float4 b = *(const float4*)(hr + c * 32 + 4);
    hb[c].x = cvtpk(a.x, a.y); hb[c].y = cvtpk(a.z, a.w);
    hb[c].z = cvtpk(b.x, b.y); hb[c].w = cvtpk(b.z, b.w);
  }
  __syncthreads();
  f32x4 acc[16];
  #pragma unroll
  for (int n = 0; n < 16; ++n) acc[n] = (f32x4){0.f, 0.f, 0.f, 0.f};
  #pragma unroll
  for (int c = 0; c < 4; ++c) {
    s16x8 bF = *(const s16x8*)&hb[c];
    #pragma unroll
    for (int n = 0; n < 16; ++n) {
      s16x8 aF = *(const s16x8*)&sWp[n * 16 + l15][c * 32 + lg * 8];
      acc[n] = __builtin_amdgcn_mfma_f32_16x16x32_bf16(aF, bF, acc[n], 0, 0, 0);
    }
  }
  u32* dst = P + (size_t)node * 64;
  #pragma unroll
  for (int n = 0; n < 16; ++n) {
    int side = n >> 3;
    int cb = (n & 7) * 16 + lg * 4;
    float a0 = acc[n][0], a1 = acc[n][1], a2 = acc[n][2], a3 = acc[n][3];
    if (side == 0) { a0 += sib[cb]; a1 += sib[cb + 1]; a2 += sib[cb + 2]; a3 += sib[cb + 3]; }
    u32 w = __builtin_amdgcn_cvt_pk_fp8_f32(PSCL * a0, PSCL * a1, 0, false);
    w = __builtin_amdgcn_cvt_pk_fp8_f32(PSCL * a2, PSCL * a3, w, true);
    dst[side * 32 + lg * 8 + (n & 7)] = w;
  }
}

// ---- small prefetch state ----
struct PfS {
  int ri, ci;
  float4 a0, a1, d0, d1;
  float p0x, p0y, p0z, p1x, p1y, p1z;
};

// ---- launch 4: persistent fused edge kernel (R13 structure, fp8 P) ----
__global__ __launch_bounds__(512, 4) void edge_kernel(
    const float* __restrict__ pos,
    const float* __restrict__ edge_attr,
    const float* __restrict__ dist,
    const float* __restrict__ c2w,
    const float* __restrict__ cn_scale,
    const int*   __restrict__ eidx,
    const u32*   __restrict__ P,       // [N][64] u32 of fp8(x8), fragment-permuted
    const u16*   __restrict__ wadWt,   // [8192]  fragment-ordered GEMM1 weights
    const u16*   __restrict__ c1Wt,    // [16384] fragment-ordered, k-permuted GEMM2 weights
    const float* __restrict__ biasp,   // [128]
    float*       __restrict__ out)
{
  __shared__ u16   sW1[8192];    // 16 KB
  __shared__ u16   sW2[16384];   // 32 KB
  __shared__ float sC1b[HD];
  __shared__ float sC2w[HD];

  const int t    = threadIdx.x;
  const int lane = t & 63;
  const int wave = t >> 6;        // 0..7
  const int l15  = lane & 15;
  const int lg   = lane >> 4;
  const int wv   = wave * 16 + l15;   // edge offset in tile, 0..127

  if (t < HD) { sC1b[t] = biasp[t]; sC2w[t] = c2w[t]; }
  {
    const uint4* s1 = (const uint4*)wadWt;   // 1024 uint4
    uint4* d1 = (uint4*)sW1;
    #pragma unroll
    for (int i = 0; i < 2; ++i) d1[t + i * 512] = s1[t + i * 512];
    const uint4* s2 = (const uint4*)c1Wt;    // 2048 uint4
    uint4* d2 = (uint4*)sW2;
    #pragma unroll
    for (int i = 0; i < 4; ++i) d2[t + i * 512] = s2[t + i * 512];
  }

  const float cns = cn_scale[0];
  const int bbase = lg * 2048 + l15 * 16;   // byte base within each 8KB k-panel

  auto pf_idx_ad = [&](PfS& p, int tile) {
    int e = tile * TB + wv;
    p.ri = eidx[e];
    p.ci = eidx[EE + e];
    const float* pa = edge_attr + (size_t)e * 32 + lg * 8;
    const float* pd = dist      + (size_t)e * 32 + lg * 8;
    p.a0 = *(const float4*)(pa); p.a1 = *(const float4*)(pa + 4);
    p.d0 = *(const float4*)(pd); p.d1 = *(const float4*)(pd + 4);
  };
  auto pf_pos = [&](PfS& p) {
    p.p0x = pos[p.ri * 3 + 0]; p.p0y = pos[p.ri * 3 + 1]; p.p0z = pos[p.ri * 3 + 2];
    p.p1x = pos[p.ci * 3 + 0]; p.p1y = pos[p.ci * 3 + 1]; p.p1z = pos[p.ci * 3 + 2];
  };

  PfS A, B;
  pf_idx_ad(A, blockIdx.x);
  pf_pos(A);

  // prologue: P gathers (fp8: 2 uint4 per side)
  uint4 pra0, pra1, pca0, pca1;
  {
    const u32* pr = P + (size_t)A.ri * 64 + lg * 8;
    const u32* pc = P + (size_t)A.ci * 64 + 32 + lg * 8;
    pra0 = *(const uint4*)(pr); pra1 = *(const uint4*)(pr + 4);
    pca0 = *(const uint4*)(pc); pca1 = *(const uint4*)(pc + 4);
  }

  __syncthreads();   // only barrier: weights + consts visible

  for (int tile = blockIdx.x; tile < NTILES; tile += GRID) {
    int tn = tile + GRID; if (tn >= NTILES) tn = tile;

    // (1) next tile's independent loads — in flight across this tile
    pf_idx_ad(B, tn);

    // (2) GEMM1: Q = [attr|dist] @ iW_ad, all-immediate-offset LDS reads
    uint4 ef0, ef1;
    ef0.x = cvtpk(A.a0.x, A.a0.y); ef0.y = cvtpk(A.a0.z, A.a0.w);
    ef0.z = cvtpk(A.a1.x, A.a1.y); ef0.w = cvtpk(A.a1.z, A.a1.w);
    ef1.x = cvtpk(A.d0.x, A.d0.y); ef1.y = cvtpk(A.d0.z, A.d0.w);
    ef1.z = cvtpk(A.d1.x, A.d1.y); ef1.w = cvtpk(A.d1.z, A.d1.w);

    f32x4 acc[8];
    #pragma unroll
    for (int n = 0; n < 8; ++n) acc[n] = (f32x4){0.f, 0.f, 0.f, 0.f};
    #pragma unroll
    for (int ks = 0; ks < 2; ++ks) {
      s16x8 bF = (ks == 0) ? *(const s16x8*)&ef0 : *(const s16x8*)&ef1;
      #pragma unroll
      for (int n = 0; n < 8; ++n) {
        s16x8 aF = *(const s16x8*)((const char*)sW1 + ks * 8192 + bbase + n * 256);
        acc[n] = __builtin_amdgcn_mfma_f32_16x16x32_bf16(aF, bF, acc[n], 0, 0, 0);
      }
    }

    // (3) x = Q + (P_r + P_c)/8; LN stats with 4-way partial accumulators
    //     fp8 word n holds exactly channels of acc[n]
    float x[8][4];
    float s0=0.f,s1=0.f,s2=0.f,s3=0.f, q0=0.f,q1=0.f,q2=0.f,q3=0.f;
    #pragma unroll
    for (int i = 0; i < 2; ++i) {
      uint4 wa = (i == 0) ? pra0 : pra1;
      uint4 wc = (i == 0) ? pca0 : pca1;
      #pragma unroll
      for (int k = 0; k < 4; ++k) {
        int n = i * 4 + k;
        u32 aw = (k == 0) ? wa.x : (k == 1) ? wa.y : (k == 2) ? wa.z : wa.w;
        u32 cw = (k == 0) ? wc.x : (k == 1) ? wc.y : (k == 2) ? wc.z : wc.w;
        f32x2 a01 = __builtin_amdgcn_cvt_pk_f32_fp8(aw, false);
        f32x2 a23 = __builtin_amdgcn_cvt_pk_f32_fp8(aw, true);
        f32x2 c01 = __builtin_amdgcn_cvt_pk_f32_fp8(cw, false);
        f32x2 c23 = __builtin_amdgcn_cvt_pk_f32_fp8(cw, true);
        float v0 = fmaf(a01[0] + c01[0], PDSC, acc[n][0]);
        float v1 = fmaf(a01[1] + c01[1], PDSC, acc[n][1]);
        float v2 = fmaf(a23[0] + c23[0], PDSC, acc[n][2]);
        float v3 = fmaf(a23[1] + c23[1], PDSC, acc[n][3]);
        x[n][0] = v0; x[n][1] = v1; x[n][2] = v2; x[n][3] = v3;
        s0 += v0; s1 += v1; s2 += v2; s3 += v3;
        q0 = fmaf(v0,v0,q0); q1 = fmaf(v1,v1,q1);
        q2 = fmaf(v2,v2,q2); q3 = fmaf(v3,v3,q3);
      }
    }
    float sum = (s0 + s1) + (s2 + s3);
    float sq  = (q0 + q1) + (q2 + q3);
    sum += __shfl_xor(sum, 16); sum += __shfl_xor(sum, 32);
    sq  += __shfl_xor(sq,  16); sq  += __shfl_xor(sq,  32);
    float mean = sum * (1.f / 128.f);
    float var  = sq  * (1.f / 128.f) - mean * mean;
    float LA = rsqrtf(var + 1e-6f);
    float LB = -mean * LA;

    union { uint2 u2[8]; u32 w[16]; } xb;
    #pragma unroll
    for (int n = 0; n < 8; ++n) {
      float y0 = fmaf(x[n][0], LA, LB);
      float y1 = fmaf(x[n][1], LA, LB);
      float y2 = fmaf(x[n][2], LA, LB);
      float y3 = fmaf(x[n][3], LA, LB);
      xb.u2[n].x = cvtpk(y0, y1);
      xb.u2[n].y = cvtpk(y2, y3);
    }

    // (4) GEMM2: reuse acc (AGPR overlap); B from registers, A via LDS
    #pragma unroll
    for (int n = 0; n < 8; ++n) acc[n] = (f32x4){0.f, 0.f, 0.f, 0.f};
    #pragma unroll
    for (int kq = 0; kq < 4; ++kq) {
      u32x4 xw = { xb.w[4*kq], xb.w[4*kq+1], xb.w[4*kq+2], xb.w[4*kq+3] };
      s16x8 xF = __builtin_bit_cast(s16x8, xw);
      #pragma unroll
      for (int n = 0; n < 8; ++n) {
        s16x8 aF = *(const s16x8*)((const char*)sW2 + kq * 8192 + bbase + n * 256);
        acc[n] = __builtin_amdgcn_mfma_f32_16x16x32_bf16(aF, xF, acc[n], 0, 0, 0);
      }
    }

    // (5) silu -> dot(c2W) with 4-way partial chains
    float z0=0.f, z1=0.f, z2=0.f, z3=0.f;
    #pragma unroll
    for (int n = 0; n < 8; ++n) {
      int cb = n * 16 + lg * 4;
      f32x4 cb4 = *(const f32x4*)&sC1b[cb];
      f32x4 cw4 = *(const f32x4*)&sC2w[cb];
      float y0 = acc[n][0] + cb4[0];
      float y1 = acc[n][1] + cb4[1];
      float y2 = acc[n][2] + cb4[2];
      float y3 = acc[n][3] + cb4[3];
      z0 = fmaf(y0 * __builtin_amdgcn_rcpf(1.f + __expf(-y0)), cw4[0], z0);
      z1 = fmaf(y1 * __builtin_amdgcn_rcpf(1.f + __expf(-y1)), cw4[1], z1);
      z2 = fmaf(y2 * __builtin_amdgcn_rcpf(1.f + __expf(-y2)), cw4[2], z2);
      z3 = fmaf(y3 * __builtin_amdgcn_rcpf(1.f + __expf(-y3)), cw4[3], z3);
    }
    float z = (z0 + z1) + (z2 + z3);
    z += __shfl_xor(z, 16); z += __shfl_xor(z, 32);

    // (6) depth-1 prefetch: next tile's pos + P words
    pf_pos(B);
    uint4 qra0, qra1, qca0, qca1;
    {
      const u32* pr = P + (size_t)B.ri * 64 + lg * 8;
      const u32* pc = P + (size_t)B.ci * 64 + 32 + lg * 8;
      qra0 = *(const uint4*)(pr); qra1 = *(const uint4*)(pr + 4);
      qca0 = *(const uint4*)(pc); qca1 = *(const uint4*)(pc + 4);
    }

    // (7) tanh -> scatter
    if (lg < 3) {
      float zc = fminf(fmaxf(z, -15.f), 15.f);
      float ez = __expf(2.f * zc);
      float inv = (ez - 1.f) * __builtin_amdgcn_rcpf(ez + 1.f);
      float dx = A.p0x - A.p1x, dy = A.p0y - A.p1y, dz = A.p0z - A.p1z;
      float nrm = sqrtf(fmaf(dx, dx, fmaf(dy, dy, dz * dz)));
      float sc  = cns * inv * __builtin_amdgcn_rcpf(fmaxf(nrm, 1e-8f));
      float d   = (lg == 0) ? dx : ((lg == 1) ? dy : dz);
      atomicAdd(out + (size_t)A.ri * 3 + lg, d * sc);
    }

    A = B;
    pra0 = qra0; pra1 = qra1;
    pca0 = qca0; pca1 = qca1;
  }
}

extern "C" void kernel_launch(void* const* d_in, const int* in_sizes, int n_in,
                              void* d_out, int out_size, void* d_ws, size_t ws_size,
                              hipStream_t stream) {
  const float* h         = (const float*)d_in[0];
  const float* pos       = (const float*)d_in[1];
  const float* edge_attr = (const float*)d_in[2];
  const float* dist      = (const float*)d_in[3];
  const float* te        = (const float*)d_in[4];
  const float* tW        = (const float*)d_in[5];
  const float* tb        = (const float*)d_in[6];
  const float* iW        = (const float*)d_in[7];
  const float* ib        = (const float*)d_in[8];
  const float* c1W       = (const float*)d_in[9];
  const float* c1b       = (const float*)d_in[10];
  const float* c2W       = (const float*)d_in[11];
  const float* cn        = (const float*)d_in[12];
  const int*   eidx      = (const int*)d_in[13];
  float* out = (float*)d_out;

  char* ws = (char*)d_ws;
  u32*   P      = (u32*)(ws);                    // 40000*256 B (fp8) = 10,240,000 B
  u16*   wPt    = (u16*)(ws + 10240000);         // 65,536 B
  u16*   wadWt  = (u16*)(ws + 10305536);         // 16,384 B
  u16*   c1Wt   = (u16*)(ws + 10321920);         // 32,768 B
  float* film   = (float*)(ws + 10354688);       // 1,024 B
  float* biasp  = (float*)(ws + 10355712);       // 512 B

  hipLaunchKernelGGL(prep_film_kernel,    dim3(1),    dim3(256), 0, stream, te, tW, tb, film);
  hipLaunchKernelGGL(prep_weights_kernel, dim3(225),  dim3(256), 0, stream,
                     iW, c1W, film, c1b, wPt, wadWt, c1Wt, biasp);
  hipLaunchKernelGGL(prep_P_kernel,       dim3(625),  dim3(256), 0, stream,
                     h, wPt, ib, pos, P, out);
  hipLaunchKernelGGL(edge_kernel,         dim3(GRID), dim3(512), 0, stream,
                     pos, edge_attr, dist, c2W, cn, eidx,
                     P, wadWt, c1Wt, biasp, out);
}